// Round 6
// baseline (554.162 us; speedup 1.0000x reference)
//
#include <hip/hip_runtime.h>
#include <hip/hip_bf16.h>

#define N_NODES 100000
#define NPAD 100032                         // 64-row-aligned node count
#define N_EDGES 1600000
#define ETOT (N_EDGES + N_NODES)
#define NFEAT 165
#define KP 192                              // K padded to 32-multiple
#define HID 128
#define NCLS 2
#define NEG 0.2f

// CSR radix-build parameters
#define NBUCK 391                           // ceil(N_NODES/256); bucket = dst >> 8
#define CHUNK 16384
#define NCHUNK 104                          // ceil(ETOT/CHUNK)

typedef short bf16x8 __attribute__((ext_vector_type(8)));
typedef float f32x4 __attribute__((ext_vector_type(4)));

// ---- workspace layout (units of 4 bytes) ----
#define OFF_FLAG 0
#define OFF_W 16
// weight sub-offsets (within wb = ws + OFF_W); only ATT1.. are populated now
#define WO_ATT1 42496
#define WO_BIAS1 42624
#define WO_W2L 42752
#define WO_B2L 43008
#define WO_W2R 43010
#define WO_B2R 43266
#define WO_ATT2 43268
#define WO_BIAS2 43270

#define OFF_XB   43392                      // (unused, kept for layout stability)
#define OFF_WT   (OFF_XB + NPAD * KP / 2)   // bf16 WT [256][192]
#define OFF_BCAT (OFF_WT + 256 * KP / 2)    // fp32 bias concat [256]
#define OFF_XLB  (OFF_BCAT + 256)           // bf16 xl rows [NPAD][128]
#define OFF_XRB  (OFF_XLB + NPAD * HID / 2) // bf16 xr rows
#define OFF_PAIRS (OFF_XRB + NPAD * HID / 2) // int2 pairs[ETOT]
#define OFF_CSR  (OFF_PAIRS + 2 * ETOT)     // csr_src[ETOT]
#define OFF_ROWPTR (OFF_CSR + ETOT)         // rowptr[N_NODES+1]
#define OFF_S    (OFF_ROWPTR + N_NODES + 8) // per-(bucket,chunk) offsets
#define OFF_XL2  (OFF_S + NBUCK * NCHUNK + 8)
#define OFF_XR2  (OFF_XL2 + N_NODES * NCLS)

__device__ __forceinline__ float bload16(unsigned short u) {
    return __uint_as_float(((unsigned)u) << 16);
}

// lrelu(v) = 0.6v + 0.4|v|
__device__ __forceinline__ float lrelu(float v) {
    return fmaf(0.4f, fabsf(v), 0.6f * v);
}

__device__ __forceinline__ void unpack8(uint4 q, float* f) {
    f[0] = __uint_as_float(q.x << 16); f[1] = __uint_as_float(q.x & 0xffff0000u);
    f[2] = __uint_as_float(q.y << 16); f[3] = __uint_as_float(q.y & 0xffff0000u);
    f[4] = __uint_as_float(q.z << 16); f[5] = __uint_as_float(q.z & 0xffff0000u);
    f[6] = __uint_as_float(q.w << 16); f[7] = __uint_as_float(q.w & 0xffff0000u);
}

__device__ __forceinline__ unsigned short f2b(float f) {
    __hip_bfloat16 b = __float2bfloat16(f);
    return *(unsigned short*)&b;
}

// wave-uniform dtype sniff: 64 halves of x; bf16 -> ~all plausible, fp32 -> ~58%
__device__ __forceinline__ unsigned detect_flag(const unsigned short* x16, int lane) {
    unsigned short hh = x16[lane];
    unsigned e = (hh >> 7) & 0xFF;
    bool pl = ((hh & 0x7FFF) == 0) || (e >= 100 && e <= 140);
    unsigned long long m = __ballot(pl);
    return (__popcll(m) >= 52) ? 1u : 0u;
}

// ---- fused prep: flag + WT/bcat (layer-1 weights, bf16) + small wb (fp32) ----
#define PREP_WT 49152                       // 256*192
#define PREP_BC (PREP_WT + 256)
#define PREP_TOT (PREP_BC + 776)
__global__ void __launch_bounds__(256) k_prep(
        const unsigned short* __restrict__ x16,
        const void* W1l, const void* b1l, const void* W1r, const void* b1r,
        const void* att1, const void* bias1, const void* W2l, const void* b2l,
        const void* W2r, const void* b2r, const void* att2, const void* bias2,
        unsigned* __restrict__ flagp, unsigned short* __restrict__ wt,
        float* __restrict__ bcat, float* __restrict__ wb) {
    int lane = threadIdx.x & 63;
    unsigned isbf = detect_flag(x16, lane);
    int i = blockIdx.x * 256 + threadIdx.x;
    if (i == 0) *flagp = isbf;
    if (i >= PREP_TOT) return;
    if (i < PREP_WT) {
        int n = i / KP, k = i - n * KP;
        unsigned short v = 0;
        if (k < NFEAT) {
            const void* src = (n < HID) ? W1l : W1r;
            size_t off = (size_t)k * HID + (n & (HID - 1));
            v = isbf ? ((const unsigned short*)src)[off]
                     : f2b(((const float*)src)[off]);
        }
        wt[i] = v;
    } else if (i < PREP_BC) {
        int n = i - PREP_WT;
        const void* src = (n < HID) ? b1l : b1r;
        int off = n & (HID - 1);
        bcat[n] = isbf ? bload16(((const unsigned short*)src)[off])
                       : ((const float*)src)[off];
    } else {
        int j = i - PREP_BC;
        const void* src; int off; int dst;
        if      (j < 128) { src = att1;  off = j;       dst = WO_ATT1 + j; }
        else if (j < 256) { src = bias1; off = j - 128; dst = WO_BIAS1 + (j - 128); }
        else if (j < 512) { src = W2l;   off = j - 256; dst = WO_W2L + (j - 256); }
        else if (j < 514) { src = b2l;   off = j - 512; dst = WO_B2L + (j - 512); }
        else if (j < 770) { src = W2r;   off = j - 514; dst = WO_W2R + (j - 514); }
        else if (j < 772) { src = b2r;   off = j - 770; dst = WO_B2R + (j - 770); }
        else if (j < 774) { src = att2;  off = j - 772; dst = WO_ATT2 + (j - 772); }
        else              { src = bias2; off = j - 774; dst = WO_BIAS2 + (j - 774); }
        wb[dst] = isbf ? bload16(((const unsigned short*)src)[off])
                       : ((const float*)src)[off];
    }
}

// ================= CSR build: two-level counting sort =================
__global__ void __launch_bounds__(256) k_pa_hist(const int* __restrict__ edst,
                                                 int* __restrict__ bh) {
    __shared__ int hist[NBUCK];
    for (int i = threadIdx.x; i < NBUCK; i += 256) hist[i] = 0;
    __syncthreads();
    int base = blockIdx.x * CHUNK;
    for (int i = threadIdx.x; i < CHUNK; i += 256) {
        int e = base + i;
        if (e >= ETOT) break;
        int d = (e < N_EDGES) ? edst[e] : (e - N_EDGES);
        atomicAdd(&hist[d >> 8], 1);
    }
    __syncthreads();
    for (int b = threadIdx.x; b < NBUCK; b += 256)
        bh[b * NCHUNK + blockIdx.x] = hist[b];
}

__global__ void __launch_bounds__(512) k_pa_scan(int* __restrict__ S,
                                                 int* __restrict__ rowptr) {
    __shared__ int lds[512];
    const int TOT = NBUCK * NCHUNK;
    const int per = (TOT + 511) / 512;
    int t = threadIdx.x;
    int beg = t * per;
    int sum = 0;
    for (int k = 0; k < per; k++) {
        int i = beg + k;
        if (i < TOT) sum += S[i];
    }
    lds[t] = sum;
    __syncthreads();
    for (int off = 1; off < 512; off <<= 1) {
        int v = lds[t];
        if (t >= off) v += lds[t - off];
        __syncthreads();
        lds[t] = v;
        __syncthreads();
    }
    int carry = (t == 0) ? 0 : lds[t - 1];
    for (int k = 0; k < per; k++) {
        int i = beg + k;
        if (i < TOT) {
            int v = S[i];
            S[i] = carry;
            carry += v;
        }
    }
    if (t == 0) rowptr[N_NODES] = ETOT;
}

__global__ void __launch_bounds__(256) k_pa_scatter(const int* __restrict__ esrc,
                                                    const int* __restrict__ edst,
                                                    const int* __restrict__ S,
                                                    int2* __restrict__ pairs) {
    __shared__ int cur[NBUCK];
    for (int i = threadIdx.x; i < NBUCK; i += 256)
        cur[i] = S[i * NCHUNK + blockIdx.x];
    __syncthreads();
    int base = blockIdx.x * CHUNK;
    for (int i = threadIdx.x; i < CHUNK; i += 256) {
        int e = base + i;
        if (e >= ETOT) break;
        int s = (e < N_EDGES) ? esrc[e] : (e - N_EDGES);
        int d = (e < N_EDGES) ? edst[e] : (e - N_EDGES);
        int p = atomicAdd(&cur[d >> 8], 1);
        pairs[p] = make_int2(s, d);
    }
}

__global__ void __launch_bounds__(256) k_bsort(const int* __restrict__ S,
                                               const int2* __restrict__ pairs,
                                               int* __restrict__ rowptr,
                                               int* __restrict__ csr) {
    __shared__ int hist[256];
    __shared__ int cur[256];
    int b = blockIdx.x, t = threadIdx.x;
    int beg = S[b * NCHUNK];
    int end = (b == NBUCK - 1) ? ETOT : S[(b + 1) * NCHUNK];
    hist[t] = 0;
    __syncthreads();
    for (int j = beg + t; j < end; j += 256)
        atomicAdd(&hist[pairs[j].y & 255], 1);
    __syncthreads();
    for (int off = 1; off < 256; off <<= 1) {
        int v = hist[t];
        if (t >= off) v += hist[t - off];
        __syncthreads();
        hist[t] = v;
        __syncthreads();
    }
    int excl = (t == 0) ? 0 : hist[t - 1];
    int node = b * 256 + t;
    if (node < N_NODES) rowptr[node] = beg + excl;
    cur[t] = beg + excl;
    __syncthreads();
    for (int j = beg + t; j < end; j += 256) {
        int2 pr = pairs[j];
        int p = atomicAdd(&cur[pr.y & 255], 1);
        csr[p] = pr.x;
    }
}

// ================= layer-1 GEMM via bf16 MFMA (x converted in staging) =======
#define XS_STRIDE 200
__global__ void __launch_bounds__(256) k_gemm1_mfma(
        const void* __restrict__ x,
        const unsigned* __restrict__ flagp,
        const unsigned short* __restrict__ wt,
        const float* __restrict__ bcat,
        __hip_bfloat16* __restrict__ xlb,
        __hip_bfloat16* __restrict__ xrb) {
    __shared__ unsigned short xs[64 * XS_STRIDE];
    int tid = threadIdx.x;
    int wave = tid >> 6, lane = tid & 63;
    int sub = lane >> 4, li = lane & 15;
    int node0 = blockIdx.x * 64;
    unsigned isbf = *flagp;
    const float* xf = (const float*)x;
    const unsigned short* x16 = (const unsigned short*)x;

    // zero pad cols [165,192) -- disjoint from fill, no barrier needed between
    for (int i = tid; i < 64 * 27; i += 256) {
        int r = i / 27, c = 165 + (i - r * 27);
        xs[r * XS_STRIDE + c] = 0;
    }
    // stage + convert 64 x-rows
    for (int i = tid; i < 64 * NFEAT; i += 256) {
        int r = i / NFEAT, c = i - r * NFEAT;
        int grow = node0 + r;
        unsigned short v = 0;
        if (grow < N_NODES) {
            size_t g = (size_t)grow * NFEAT + c;
            v = isbf ? x16[g] : f2b(xf[g]);
        }
        xs[r * XS_STRIDE + c] = v;
    }

    bf16x8 bfrag[4][6];
#pragma unroll
    for (int q = 0; q < 4; q++) {
        int n = wave * 64 + q * 16 + li;
#pragma unroll
        for (int kk = 0; kk < 6; kk++)
            bfrag[q][kk] = *(const bf16x8*)&wt[(size_t)n * KP + kk * 32 + sub * 8];
    }
    float bias[4];
#pragma unroll
    for (int q = 0; q < 4; q++) bias[q] = bcat[wave * 64 + q * 16 + li];
    __syncthreads();

    for (int mt = 0; mt < 4; mt++) {
        bf16x8 afrag[6];
#pragma unroll
        for (int kk = 0; kk < 6; kk++)
            afrag[kk] = *(const bf16x8*)&xs[(mt * 16 + li) * XS_STRIDE + kk * 32 + sub * 8];
#pragma unroll
        for (int q = 0; q < 4; q++) {
            f32x4 a = {0.f, 0.f, 0.f, 0.f};
#pragma unroll
            for (int kk = 0; kk < 6; kk++)
                a = __builtin_amdgcn_mfma_f32_16x16x32_bf16(afrag[kk], bfrag[q][kk], a, 0, 0, 0);
            int n = wave * 64 + q * 16 + li;
            __hip_bfloat16* dst = (n < HID) ? xlb : xrb;
            int nc = n & (HID - 1);
#pragma unroll
            for (int r = 0; r < 4; r++) {
                int row = node0 + mt * 16 + sub * 4 + r;
                dst[(size_t)row * HID + nc] = __float2bfloat16(a[r] + bias[q]);
            }
        }
    }
}

// ================= fused layer-1 attention + layer-2 GEMM epilogue ==========
// One wave per dst node; 4 edges in flight (16 lanes x 8 dims). Softmax without
// max-subtraction (scores are O(1)). Epilogue: h stays in registers; each
// 16-lane subgroup computes one of {xl2[0],xl2[1],xr2[0],xr2[1]}.
__global__ void __launch_bounds__(256) k_gat1(const int* __restrict__ rowptr,
                                              const int* __restrict__ csr,
                                              const __hip_bfloat16* __restrict__ xlb,
                                              const __hip_bfloat16* __restrict__ xrb,
                                              const float* __restrict__ wb,
                                              float* __restrict__ xl2,
                                              float* __restrict__ xr2) {
    int wave = threadIdx.x >> 6, lane = threadIdx.x & 63;
    int d = blockIdx.x * 4 + wave;
    if (d >= N_NODES) return;
    int sub = lane >> 4, li = lane & 15;

    uint4 qr = ((const uint4*)(xrb + (size_t)d * HID))[li];
    float xrv[8]; unpack8(qr, xrv);
    const float* att = wb + WO_ATT1;
    const float* bias1 = wb + WO_BIAS1;
    float atv06[8], atv04[8], biasv[8], w2[8];
    {
        float4 t0 = ((const float4*)att)[li * 2];
        float4 t1 = ((const float4*)att)[li * 2 + 1];
        float a[8] = {t0.x, t0.y, t0.z, t0.w, t1.x, t1.y, t1.z, t1.w};
#pragma unroll
        for (int t = 0; t < 8; t++) { atv06[t] = 0.6f * a[t]; atv04[t] = 0.4f * a[t]; }
        float4 b0 = ((const float4*)bias1)[li * 2];
        float4 b1 = ((const float4*)bias1)[li * 2 + 1];
        biasv[0] = b0.x; biasv[1] = b0.y; biasv[2] = b0.z; biasv[3] = b0.w;
        biasv[4] = b1.x; biasv[5] = b1.y; biasv[6] = b1.z; biasv[7] = b1.w;
    }
    const float* wsel = (sub < 2) ? (wb + WO_W2L) : (wb + WO_W2R);
    int cls = sub & 1;
#pragma unroll
    for (int t = 0; t < 8; t++) w2[t] = wsel[(li * 8 + t) * 2 + cls];
    float outb = (sub < 2) ? wb[WO_B2L + cls] : wb[WO_B2R + cls];

    int beg = rowptr[d], end = rowptr[d + 1];
    int iters = (end - beg + 3) >> 2;
    float l = 0.f, o[8];
#pragma unroll
    for (int t = 0; t < 8; t++) o[t] = 0.f;

    int j = beg + sub;
    bool valid = j < end;
    int s = valid ? csr[j] : 0;
    uint4 q = *(const uint4*)(xlb + (size_t)s * HID + li * 8);

    for (int it = 0; it < iters; it++) {
        float c[8]; unpack8(q, c);
        bool v = valid;
        j += 4;
        valid = j < end;
        int sn = valid ? csr[j] : 0;
        q = *(const uint4*)(xlb + (size_t)sn * HID + li * 8);

        float p = 0.f;
#pragma unroll
        for (int t = 0; t < 8; t++) {
            float vv = c[t] + xrv[t];
            p = fmaf(atv04[t], fabsf(vv), p);
            p = fmaf(atv06[t], vv, p);
        }
        p += __shfl_xor(p, 1);
        p += __shfl_xor(p, 2);
        p += __shfl_xor(p, 4);
        p += __shfl_xor(p, 8);
        float a = v ? __expf(p) : 0.f;
        l += a;
#pragma unroll
        for (int t = 0; t < 8; t++) o[t] = fmaf(a, c[t], o[t]);
    }
    // merge the 4 subgroups -> every lane holds full sums for its li slice
    l += __shfl_xor(l, 16);
    l += __shfl_xor(l, 32);
#pragma unroll
    for (int t = 0; t < 8; t++) {
        o[t] += __shfl_xor(o[t], 16);
        o[t] += __shfl_xor(o[t], 32);
    }
    // epilogue: h = relu(o/l + bias1) in regs; subgroup 'sub' computes output
    // column cls of W2l (sub<2) or W2r (sub>=2)
    float inv = 1.f / l;  // self-loop guarantees l > 0
    float pr = 0.f;
#pragma unroll
    for (int t = 0; t < 8; t++) {
        float hv = fmaf(o[t], inv, biasv[t]);
        hv = fmaxf(hv, 0.f);
        pr = fmaf(hv, w2[t], pr);
    }
    pr += __shfl_xor(pr, 1);
    pr += __shfl_xor(pr, 2);
    pr += __shfl_xor(pr, 4);
    pr += __shfl_xor(pr, 8);
    if (li == 0) {
        float* basep = (sub < 2) ? xl2 : xr2;
        basep[2 * d + cls] = pr + outb;
    }
}

// ================= fused layer-2 attention: thread per dst node ==============
__global__ void __launch_bounds__(256) k_gat2(const int* __restrict__ rowptr,
                                              const int* __restrict__ csr,
                                              const float* __restrict__ xl2,
                                              const float* __restrict__ xr2,
                                              const float* __restrict__ wb,
                                              const unsigned* __restrict__ flag,
                                              void* __restrict__ dout) {
    int d = blockIdx.x * 256 + threadIdx.x;
    if (d >= N_NODES) return;
    float xr0 = xr2[d * 2 + 0], xr1 = xr2[d * 2 + 1];
    float at0 = wb[WO_ATT2], at1 = wb[WO_ATT2 + 1];
    int beg = rowptr[d], end = rowptr[d + 1];
    float l = 0.f, o0 = 0.f, o1 = 0.f;
    for (int j = beg; j < end; j++) {
        int s = csr[j];
        float b0 = xl2[s * 2 + 0], b1 = xl2[s * 2 + 1];
        float p = at0 * lrelu(b0 + xr0) + at1 * lrelu(b1 + xr1);
        float a = __expf(p);
        l += a;
        o0 = fmaf(a, b0, o0);
        o1 = fmaf(a, b1, o1);
    }
    float inv = 1.f / l;
    float v0 = fmaf(o0, inv, wb[WO_BIAS2 + 0]);
    float v1 = fmaf(o1, inv, wb[WO_BIAS2 + 1]);
    if (*flag) {
        ((__hip_bfloat16*)dout)[d * 2 + 0] = __float2bfloat16(v0);
        ((__hip_bfloat16*)dout)[d * 2 + 1] = __float2bfloat16(v1);
    } else {
        ((float*)dout)[d * 2 + 0] = v0;
        ((float*)dout)[d * 2 + 1] = v1;
    }
}

extern "C" void kernel_launch(void* const* d_in, const int* in_sizes, int n_in,
                              void* d_out, int out_size, void* d_ws, size_t ws_size,
                              hipStream_t stream) {
    char* w = (char*)d_ws;
    unsigned* flag = (unsigned*)(w + (size_t)OFF_FLAG * 4);
    float* wb = (float*)(w + (size_t)OFF_W * 4);
    unsigned short* wt = (unsigned short*)(w + (size_t)OFF_WT * 4);
    float* bcat = (float*)(w + (size_t)OFF_BCAT * 4);
    __hip_bfloat16* xlb = (__hip_bfloat16*)(w + (size_t)OFF_XLB * 4);
    __hip_bfloat16* xrb = (__hip_bfloat16*)(w + (size_t)OFF_XRB * 4);
    int2* pairs = (int2*)(w + (size_t)OFF_PAIRS * 4);
    int* csr = (int*)(w + (size_t)OFF_CSR * 4);
    int* rowptr = (int*)(w + (size_t)OFF_ROWPTR * 4);
    int* S = (int*)(w + (size_t)OFF_S * 4);
    float* xl2 = (float*)(w + (size_t)OFF_XL2 * 4);
    float* xr2 = (float*)(w + (size_t)OFF_XR2 * 4);
    const int* esrc = (const int*)d_in[1];
    const int* edst = (const int*)d_in[2];

    k_prep<<<(PREP_TOT + 255) / 256, 256, 0, stream>>>(
        (const unsigned short*)d_in[0],
        d_in[3], d_in[4], d_in[5], d_in[6], d_in[7], d_in[8],
        d_in[9], d_in[10], d_in[11], d_in[12], d_in[13], d_in[14],
        flag, wt, bcat, wb);

    // ---- layer-1 GEMM (x converted in staging) ----
    k_gemm1_mfma<<<NPAD / 64, 256, 0, stream>>>(d_in[0], flag, wt, bcat, xlb, xrb);

    // ---- CSR build: two-level counting sort (shared by both layers) ----
    k_pa_hist<<<NCHUNK, 256, 0, stream>>>(edst, S);
    k_pa_scan<<<1, 512, 0, stream>>>(S, rowptr);
    k_pa_scatter<<<NCHUNK, 256, 0, stream>>>(esrc, edst, S, pairs);
    k_bsort<<<NBUCK, 256, 0, stream>>>(S, pairs, rowptr, csr);

    // ---- fused layer-1 attention + layer-2 projection ----
    k_gat1<<<(N_NODES + 3) / 4, 256, 0, stream>>>(rowptr, csr, xlb, xrb, wb,
                                                  xl2, xr2);

    // ---- layer-2 attention + output ----
    k_gat2<<<(N_NODES + 255) / 256, 256, 0, stream>>>(rowptr, csr, xl2, xr2,
                                                      wb, flag, d_out);
}

// Round 7
// 526.618 us; speedup vs baseline: 1.0523x; 1.0523x over previous
//
#include <hip/hip_runtime.h>
#include <hip/hip_bf16.h>

#define N_NODES 100000
#define NPAD 100032                         // 64-row-aligned node count
#define N_EDGES 1600000
#define ETOT (N_EDGES + N_NODES)
#define NFEAT 165
#define KP 192                              // K padded to 32-multiple
#define HID 128
#define NCLS 2
#define NEG 0.2f

// CSR radix-build parameters
#define NBUCK 391                           // ceil(N_NODES/256); bucket = dst >> 8
#define CHUNK 16384
#define NCHUNK 104                          // ceil(ETOT/CHUNK)

typedef short bf16x8 __attribute__((ext_vector_type(8)));
typedef float f32x4 __attribute__((ext_vector_type(4)));

// ---- workspace layout (units of 4 bytes) ----
#define OFF_FLAG 0
#define OFF_W 16
// weight sub-offsets (within wb = ws + OFF_W)
#define WO_ATT1 42496
#define WO_BIAS1 42624
#define WO_W2L 42752
#define WO_B2L 43008
#define WO_W2R 43010
#define WO_B2R 43266
#define WO_ATT2 43268
#define WO_BIAS2 43270

#define OFF_XB   43392
#define OFF_WT   (OFF_XB + NPAD * KP / 2)   // bf16 WT [256][192]
#define OFF_BCAT (OFF_WT + 256 * KP / 2)    // fp32 bias concat [256]
#define OFF_XLB  (OFF_BCAT + 256)           // bf16 xl rows [NPAD][128]
#define OFF_XRB  (OFF_XLB + NPAD * HID / 2) // bf16 xr rows
#define OFF_PAIRS (OFF_XRB + NPAD * HID / 2) // int2 pairs[ETOT]
#define OFF_CSR  (OFF_PAIRS + 2 * ETOT)     // csr_src[ETOT]
#define OFF_ROWPTR (OFF_CSR + ETOT)         // rowptr[N_NODES+1]
#define OFF_S    (OFF_ROWPTR + N_NODES + 8) // per-(bucket,chunk) offsets
#define OFF_XL2  (OFF_S + NBUCK * NCHUNK + 8)
#define OFF_XR2  (OFF_XL2 + N_NODES * NCLS)

__device__ __forceinline__ float bload16(unsigned short u) {
    return __uint_as_float(((unsigned)u) << 16);
}

// lrelu(v) = 0.6v + 0.4|v|
__device__ __forceinline__ float lrelu(float v) {
    return fmaf(0.4f, fabsf(v), 0.6f * v);
}

__device__ __forceinline__ void unpack8(uint4 q, float* f) {
    f[0] = __uint_as_float(q.x << 16); f[1] = __uint_as_float(q.x & 0xffff0000u);
    f[2] = __uint_as_float(q.y << 16); f[3] = __uint_as_float(q.y & 0xffff0000u);
    f[4] = __uint_as_float(q.z << 16); f[5] = __uint_as_float(q.z & 0xffff0000u);
    f[6] = __uint_as_float(q.w << 16); f[7] = __uint_as_float(q.w & 0xffff0000u);
}

__device__ __forceinline__ unsigned short f2b(float f) {
    __hip_bfloat16 b = __float2bfloat16(f);
    return *(unsigned short*)&b;
}

// wave-uniform dtype sniff: 64 halves of x; bf16 -> ~all plausible, fp32 -> ~58%
__device__ __forceinline__ unsigned detect_flag(const unsigned short* x16, int lane) {
    unsigned short hh = x16[lane];
    unsigned e = (hh >> 7) & 0xFF;
    bool pl = ((hh & 0x7FFF) == 0) || (e >= 100 && e <= 140);
    unsigned long long m = __ballot(pl);
    return (__popcll(m) >= 52) ? 1u : 0u;
}

// ---- fused prep: flag + WT/bcat (layer-1 weights, bf16) + small wb (fp32) ----
#define PREP_WT 49152                       // 256*192
#define PREP_BC (PREP_WT + 256)
#define PREP_TOT (PREP_BC + 776)
__global__ void __launch_bounds__(256) k_prep(
        const unsigned short* __restrict__ x16,
        const void* W1l, const void* b1l, const void* W1r, const void* b1r,
        const void* att1, const void* bias1, const void* W2l, const void* b2l,
        const void* W2r, const void* b2r, const void* att2, const void* bias2,
        unsigned* __restrict__ flagp, unsigned short* __restrict__ wt,
        float* __restrict__ bcat, float* __restrict__ wb) {
    int lane = threadIdx.x & 63;
    unsigned isbf = detect_flag(x16, lane);
    int i = blockIdx.x * 256 + threadIdx.x;
    if (i == 0) *flagp = isbf;
    if (i >= PREP_TOT) return;
    if (i < PREP_WT) {
        int n = i / KP, k = i - n * KP;
        unsigned short v = 0;
        if (k < NFEAT) {
            const void* src = (n < HID) ? W1l : W1r;
            size_t off = (size_t)k * HID + (n & (HID - 1));
            v = isbf ? ((const unsigned short*)src)[off]
                     : f2b(((const float*)src)[off]);
        }
        wt[i] = v;
    } else if (i < PREP_BC) {
        int n = i - PREP_WT;
        const void* src = (n < HID) ? b1l : b1r;
        int off = n & (HID - 1);
        bcat[n] = isbf ? bload16(((const unsigned short*)src)[off])
                       : ((const float*)src)[off];
    } else {
        int j = i - PREP_BC;
        const void* src; int off; int dst;
        if      (j < 128) { src = att1;  off = j;       dst = WO_ATT1 + j; }
        else if (j < 256) { src = bias1; off = j - 128; dst = WO_BIAS1 + (j - 128); }
        else if (j < 512) { src = W2l;   off = j - 256; dst = WO_W2L + (j - 256); }
        else if (j < 514) { src = b2l;   off = j - 512; dst = WO_B2L + (j - 512); }
        else if (j < 770) { src = W2r;   off = j - 514; dst = WO_W2R + (j - 514); }
        else if (j < 772) { src = b2r;   off = j - 770; dst = WO_B2R + (j - 770); }
        else if (j < 774) { src = att2;  off = j - 772; dst = WO_ATT2 + (j - 772); }
        else              { src = bias2; off = j - 774; dst = WO_BIAS2 + (j - 774); }
        wb[dst] = isbf ? bload16(((const unsigned short*)src)[off])
                       : ((const float*)src)[off];
    }
}

// ================= CSR build: two-level counting sort =================
__global__ void __launch_bounds__(256) k_pa_hist(const int* __restrict__ edst,
                                                 int* __restrict__ bh) {
    __shared__ int hist[NBUCK];
    for (int i = threadIdx.x; i < NBUCK; i += 256) hist[i] = 0;
    __syncthreads();
    int base = blockIdx.x * CHUNK;
    for (int i = threadIdx.x; i < CHUNK; i += 256) {
        int e = base + i;
        if (e >= ETOT) break;
        int d = (e < N_EDGES) ? edst[e] : (e - N_EDGES);
        atomicAdd(&hist[d >> 8], 1);
    }
    __syncthreads();
    for (int b = threadIdx.x; b < NBUCK; b += 256)
        bh[b * NCHUNK + blockIdx.x] = hist[b];
}

__global__ void __launch_bounds__(512) k_pa_scan(int* __restrict__ S,
                                                 int* __restrict__ rowptr) {
    __shared__ int lds[512];
    const int TOT = NBUCK * NCHUNK;
    const int per = (TOT + 511) / 512;
    int t = threadIdx.x;
    int beg = t * per;
    int sum = 0;
    for (int k = 0; k < per; k++) {
        int i = beg + k;
        if (i < TOT) sum += S[i];
    }
    lds[t] = sum;
    __syncthreads();
    for (int off = 1; off < 512; off <<= 1) {
        int v = lds[t];
        if (t >= off) v += lds[t - off];
        __syncthreads();
        lds[t] = v;
        __syncthreads();
    }
    int carry = (t == 0) ? 0 : lds[t - 1];
    for (int k = 0; k < per; k++) {
        int i = beg + k;
        if (i < TOT) {
            int v = S[i];
            S[i] = carry;
            carry += v;
        }
    }
    if (t == 0) rowptr[N_NODES] = ETOT;
}

__global__ void __launch_bounds__(256) k_pa_scatter(const int* __restrict__ esrc,
                                                    const int* __restrict__ edst,
                                                    const int* __restrict__ S,
                                                    int2* __restrict__ pairs) {
    __shared__ int cur[NBUCK];
    for (int i = threadIdx.x; i < NBUCK; i += 256)
        cur[i] = S[i * NCHUNK + blockIdx.x];
    __syncthreads();
    int base = blockIdx.x * CHUNK;
    for (int i = threadIdx.x; i < CHUNK; i += 256) {
        int e = base + i;
        if (e >= ETOT) break;
        int s = (e < N_EDGES) ? esrc[e] : (e - N_EDGES);
        int d = (e < N_EDGES) ? edst[e] : (e - N_EDGES);
        int p = atomicAdd(&cur[d >> 8], 1);
        pairs[p] = make_int2(s, d);
    }
}

__global__ void __launch_bounds__(256) k_bsort(const int* __restrict__ S,
                                               const int2* __restrict__ pairs,
                                               int* __restrict__ rowptr,
                                               int* __restrict__ csr) {
    __shared__ int hist[256];
    __shared__ int cur[256];
    int b = blockIdx.x, t = threadIdx.x;
    int beg = S[b * NCHUNK];
    int end = (b == NBUCK - 1) ? ETOT : S[(b + 1) * NCHUNK];
    hist[t] = 0;
    __syncthreads();
    for (int j = beg + t; j < end; j += 256)
        atomicAdd(&hist[pairs[j].y & 255], 1);
    __syncthreads();
    for (int off = 1; off < 256; off <<= 1) {
        int v = hist[t];
        if (t >= off) v += hist[t - off];
        __syncthreads();
        hist[t] = v;
        __syncthreads();
    }
    int excl = (t == 0) ? 0 : hist[t - 1];
    int node = b * 256 + t;
    if (node < N_NODES) rowptr[node] = beg + excl;
    cur[t] = beg + excl;
    __syncthreads();
    for (int j = beg + t; j < end; j += 256) {
        int2 pr = pairs[j];
        int p = atomicAdd(&cur[pr.y & 255], 1);
        csr[p] = pr.x;
    }
}

// ================= layer-1 GEMM via bf16 MFMA (C^T trick for coalesced C) ====
// Operand swap: mfma(wfrag, xfrag) computes D[m=col][n=node] = C^T, so each
// lane holds 4 CONSECUTIVE output columns (quad*4+r) of one node row (li)
// -> one packed 8-B store per tile, wave-uniform xlb/xrb side.
#define XS_STRIDE 200
__global__ void __launch_bounds__(256) k_gemm1_mfma(
        const void* __restrict__ x,
        const unsigned* __restrict__ flagp,
        const unsigned short* __restrict__ wt,
        const float* __restrict__ bcat,
        __hip_bfloat16* __restrict__ xlb,
        __hip_bfloat16* __restrict__ xrb) {
    __shared__ unsigned short xs[64 * XS_STRIDE];
    int tid = threadIdx.x;
    int wave = tid >> 6, lane = tid & 63;
    int quad = lane >> 4, li = lane & 15;
    int node0 = blockIdx.x * 64;
    unsigned isbf = *flagp;
    const float* xf = (const float*)x;
    const unsigned short* x16 = (const unsigned short*)x;

    // zero pad cols [165,192)
    for (int i = tid; i < 64 * 27; i += 256) {
        int r = i / 27, c = 165 + (i - r * 27);
        xs[r * XS_STRIDE + c] = 0;
    }
    // stage + convert 64 x-rows
    for (int i = tid; i < 64 * NFEAT; i += 256) {
        int r = i / NFEAT, c = i - r * NFEAT;
        int grow = node0 + r;
        unsigned short v = 0;
        if (grow < N_NODES) {
            size_t g = (size_t)grow * NFEAT + c;
            v = isbf ? x16[g] : f2b(xf[g]);
        }
        xs[r * XS_STRIDE + c] = v;
    }

    // W fragments (used as the A operand): lane li holds W^T[col][k]
    bf16x8 wfrag[4][6];
#pragma unroll
    for (int q = 0; q < 4; q++) {
        int n = wave * 64 + q * 16 + li;
#pragma unroll
        for (int kk = 0; kk < 6; kk++)
            wfrag[q][kk] = *(const bf16x8*)&wt[(size_t)n * KP + kk * 32 + quad * 8];
    }
    float4 bv[4];
#pragma unroll
    for (int q = 0; q < 4; q++)
        bv[q] = *(const float4*)&bcat[wave * 64 + q * 16 + quad * 4];
    __syncthreads();

    for (int mt = 0; mt < 4; mt++) {
        bf16x8 xfrag[6];
#pragma unroll
        for (int kk = 0; kk < 6; kk++)
            xfrag[kk] = *(const bf16x8*)&xs[(mt * 16 + li) * XS_STRIDE + kk * 32 + quad * 8];
        int node = node0 + mt * 16 + li;
        __hip_bfloat16* dst = (wave < 2) ? xlb : xrb;
#pragma unroll
        for (int q = 0; q < 4; q++) {
            f32x4 a = {0.f, 0.f, 0.f, 0.f};
#pragma unroll
            for (int kk = 0; kk < 6; kk++)
                a = __builtin_amdgcn_mfma_f32_16x16x32_bf16(wfrag[q][kk], xfrag[kk], a, 0, 0, 0);
            unsigned short s0 = f2b(a[0] + bv[q].x), s1 = f2b(a[1] + bv[q].y);
            unsigned short s2 = f2b(a[2] + bv[q].z), s3 = f2b(a[3] + bv[q].w);
            uint2 val = { (unsigned)s0 | ((unsigned)s1 << 16),
                          (unsigned)s2 | ((unsigned)s3 << 16) };
            int col = (wave & 1) * 64 + q * 16 + quad * 4;
            *(uint2*)&dst[(size_t)node * HID + col] = val;
        }
    }
}

// ================= fused layer-1 attention + layer-2 GEMM epilogue ==========
// Loop body is the verified R4 form (8-FMA p-chain, minimal live registers);
// ALL epilogue-only loads happen after the loop.
__global__ void __launch_bounds__(256) k_gat1(const int* __restrict__ rowptr,
                                              const int* __restrict__ csr,
                                              const __hip_bfloat16* __restrict__ xlb,
                                              const __hip_bfloat16* __restrict__ xrb,
                                              const float* __restrict__ wb,
                                              float* __restrict__ xl2,
                                              float* __restrict__ xr2) {
    int wave = threadIdx.x >> 6, lane = threadIdx.x & 63;
    int d = blockIdx.x * 4 + wave;
    if (d >= N_NODES) return;
    int sub = lane >> 4, li = lane & 15;

    uint4 qr = ((const uint4*)(xrb + (size_t)d * HID))[li];
    float xrv[8]; unpack8(qr, xrv);
    const float* att = wb + WO_ATT1;
    float atv[8];
    {
        float4 t0 = ((const float4*)att)[li * 2];
        float4 t1 = ((const float4*)att)[li * 2 + 1];
        atv[0] = t0.x; atv[1] = t0.y; atv[2] = t0.z; atv[3] = t0.w;
        atv[4] = t1.x; atv[5] = t1.y; atv[6] = t1.z; atv[7] = t1.w;
    }
    int beg = rowptr[d], end = rowptr[d + 1];
    int iters = (end - beg + 3) >> 2;
    float l = 0.f, o[8];
#pragma unroll
    for (int t = 0; t < 8; t++) o[t] = 0.f;

    int j = beg + sub;
    bool valid = j < end;
    int s = valid ? csr[j] : 0;
    uint4 q = *(const uint4*)(xlb + (size_t)s * HID + li * 8);

    for (int it = 0; it < iters; it++) {
        float c[8]; unpack8(q, c);
        bool v = valid;
        j += 4;
        valid = j < end;
        int sn = valid ? csr[j] : 0;
        q = *(const uint4*)(xlb + (size_t)sn * HID + li * 8);

        float p = 0.f;
#pragma unroll
        for (int t = 0; t < 8; t++) p = fmaf(atv[t], lrelu(c[t] + xrv[t]), p);
        p += __shfl_xor(p, 1);
        p += __shfl_xor(p, 2);
        p += __shfl_xor(p, 4);
        p += __shfl_xor(p, 8);
        float a = v ? __expf(p) : 0.f;
        l += a;
#pragma unroll
        for (int t = 0; t < 8; t++) o[t] = fmaf(a, c[t], o[t]);
    }
    // merge the 4 subgroups
    l += __shfl_xor(l, 16);
    l += __shfl_xor(l, 32);
#pragma unroll
    for (int t = 0; t < 8; t++) {
        o[t] += __shfl_xor(o[t], 16);
        o[t] += __shfl_xor(o[t], 32);
    }
    // ---- epilogue (loads only touched here, after the hot loop) ----
    float inv = 1.f / l;  // self-loop guarantees l > 0
    const float* bias1 = wb + WO_BIAS1;
    float4 b0 = ((const float4*)bias1)[li * 2];
    float4 b1 = ((const float4*)bias1)[li * 2 + 1];
    float hv[8];
    hv[0] = fmaxf(fmaf(o[0], inv, b0.x), 0.f);
    hv[1] = fmaxf(fmaf(o[1], inv, b0.y), 0.f);
    hv[2] = fmaxf(fmaf(o[2], inv, b0.z), 0.f);
    hv[3] = fmaxf(fmaf(o[3], inv, b0.w), 0.f);
    hv[4] = fmaxf(fmaf(o[4], inv, b1.x), 0.f);
    hv[5] = fmaxf(fmaf(o[5], inv, b1.y), 0.f);
    hv[6] = fmaxf(fmaf(o[6], inv, b1.z), 0.f);
    hv[7] = fmaxf(fmaf(o[7], inv, b1.w), 0.f);
    const float* wsel = (sub < 2) ? (wb + WO_W2L) : (wb + WO_W2R);
    int cls = sub & 1;
    float pr = 0.f;
#pragma unroll
    for (int t = 0; t < 8; t++) pr = fmaf(hv[t], wsel[(li * 8 + t) * 2 + cls], pr);
    pr += __shfl_xor(pr, 1);
    pr += __shfl_xor(pr, 2);
    pr += __shfl_xor(pr, 4);
    pr += __shfl_xor(pr, 8);
    if (li == 0) {
        float outb = (sub < 2) ? wb[WO_B2L + cls] : wb[WO_B2R + cls];
        float* basep = (sub < 2) ? xl2 : xr2;
        basep[2 * d + cls] = pr + outb;
    }
}

// ================= fused layer-2 attention: thread per dst node ==============
__global__ void __launch_bounds__(256) k_gat2(const int* __restrict__ rowptr,
                                              const int* __restrict__ csr,
                                              const float* __restrict__ xl2,
                                              const float* __restrict__ xr2,
                                              const float* __restrict__ wb,
                                              const unsigned* __restrict__ flag,
                                              void* __restrict__ dout) {
    int d = blockIdx.x * 256 + threadIdx.x;
    if (d >= N_NODES) return;
    float xr0 = xr2[d * 2 + 0], xr1 = xr2[d * 2 + 1];
    float at0 = wb[WO_ATT2], at1 = wb[WO_ATT2 + 1];
    int beg = rowptr[d], end = rowptr[d + 1];
    float l = 0.f, o0 = 0.f, o1 = 0.f;
    for (int j = beg; j < end; j++) {
        int s = csr[j];
        float b0 = xl2[s * 2 + 0], b1 = xl2[s * 2 + 1];
        float p = at0 * lrelu(b0 + xr0) + at1 * lrelu(b1 + xr1);
        float a = __expf(p);
        l += a;
        o0 = fmaf(a, b0, o0);
        o1 = fmaf(a, b1, o1);
    }
    float inv = 1.f / l;
    float v0 = fmaf(o0, inv, wb[WO_BIAS2 + 0]);
    float v1 = fmaf(o1, inv, wb[WO_BIAS2 + 1]);
    if (*flag) {
        ((__hip_bfloat16*)dout)[d * 2 + 0] = __float2bfloat16(v0);
        ((__hip_bfloat16*)dout)[d * 2 + 1] = __float2bfloat16(v1);
    } else {
        ((float*)dout)[d * 2 + 0] = v0;
        ((float*)dout)[d * 2 + 1] = v1;
    }
}

extern "C" void kernel_launch(void* const* d_in, const int* in_sizes, int n_in,
                              void* d_out, int out_size, void* d_ws, size_t ws_size,
                              hipStream_t stream) {
    char* w = (char*)d_ws;
    unsigned* flag = (unsigned*)(w + (size_t)OFF_FLAG * 4);
    float* wb = (float*)(w + (size_t)OFF_W * 4);
    unsigned short* wt = (unsigned short*)(w + (size_t)OFF_WT * 4);
    float* bcat = (float*)(w + (size_t)OFF_BCAT * 4);
    __hip_bfloat16* xlb = (__hip_bfloat16*)(w + (size_t)OFF_XLB * 4);
    __hip_bfloat16* xrb = (__hip_bfloat16*)(w + (size_t)OFF_XRB * 4);
    int2* pairs = (int2*)(w + (size_t)OFF_PAIRS * 4);
    int* csr = (int*)(w + (size_t)OFF_CSR * 4);
    int* rowptr = (int*)(w + (size_t)OFF_ROWPTR * 4);
    int* S = (int*)(w + (size_t)OFF_S * 4);
    float* xl2 = (float*)(w + (size_t)OFF_XL2 * 4);
    float* xr2 = (float*)(w + (size_t)OFF_XR2 * 4);
    const int* esrc = (const int*)d_in[1];
    const int* edst = (const int*)d_in[2];

    k_prep<<<(PREP_TOT + 255) / 256, 256, 0, stream>>>(
        (const unsigned short*)d_in[0],
        d_in[3], d_in[4], d_in[5], d_in[6], d_in[7], d_in[8],
        d_in[9], d_in[10], d_in[11], d_in[12], d_in[13], d_in[14],
        flag, wt, bcat, wb);

    // ---- layer-1 GEMM (x converted in staging; C^T coalesced stores) ----
    k_gemm1_mfma<<<NPAD / 64, 256, 0, stream>>>(d_in[0], flag, wt, bcat, xlb, xrb);

    // ---- CSR build: two-level counting sort (shared by both layers) ----
    k_pa_hist<<<NCHUNK, 256, 0, stream>>>(edst, S);
    k_pa_scan<<<1, 512, 0, stream>>>(S, rowptr);
    k_pa_scatter<<<NCHUNK, 256, 0, stream>>>(esrc, edst, S, pairs);
    k_bsort<<<NBUCK, 256, 0, stream>>>(S, pairs, rowptr, csr);

    // ---- fused layer-1 attention + layer-2 projection ----
    k_gat1<<<(N_NODES + 3) / 4, 256, 0, stream>>>(rowptr, csr, xlb, xrb, wb,
                                                  xl2, xr2);

    // ---- layer-2 attention + output ----
    k_gat2<<<(N_NODES + 255) / 256, 256, 0, stream>>>(rowptr, csr, xl2, xr2,
                                                      wb, flag, d_out);
}

// Round 8
// 468.830 us; speedup vs baseline: 1.1820x; 1.1233x over previous
//
#include <hip/hip_runtime.h>
#include <hip/hip_bf16.h>

#define N_NODES 100000
#define NPAD 100032                         // 64-row-aligned node count
#define N_EDGES 1600000
#define ETOT (N_EDGES + N_NODES)
#define NFEAT 165
#define KP 192                              // K padded to 32-multiple
#define HID 128
#define NCLS 2
#define NEG 0.2f

// CSR radix-build parameters
#define NBUCK 391                           // ceil(N_NODES/256); bucket = dst >> 8
#define CHUNK 16384
#define NCHUNK 104                          // ceil(ETOT/CHUNK)

typedef short bf16x8 __attribute__((ext_vector_type(8)));
typedef float f32x4 __attribute__((ext_vector_type(4)));

// ---- workspace layout (units of 4 bytes) ----
#define OFF_FLAG 0
#define OFF_W 16
// weight sub-offsets (within wb = ws + OFF_W)
#define WO_ATT1 42496
#define WO_BIAS1 42624
#define WO_W2L 42752
#define WO_B2L 43008
#define WO_W2R 43010
#define WO_B2R 43266
#define WO_ATT2 43268
#define WO_BIAS2 43270

#define OFF_XB   43392
#define OFF_WT   (OFF_XB + NPAD * KP / 2)   // bf16 WT [256][192]
#define OFF_BCAT (OFF_WT + 256 * KP / 2)    // fp32 bias concat [256]
#define OFF_XLB  (OFF_BCAT + 256)           // bf16 xl rows [NPAD][128]
#define OFF_XRB  (OFF_XLB + NPAD * HID / 2) // bf16 xr rows
#define OFF_PAIRS (OFF_XRB + NPAD * HID / 2) // int2 pairs[ETOT]
#define OFF_CSR  (OFF_PAIRS + 2 * ETOT)     // csr_src[ETOT]
#define OFF_ROWPTR (OFF_CSR + ETOT)         // rowptr[N_NODES+1]
#define OFF_S    (OFF_ROWPTR + N_NODES + 8) // per-(bucket,chunk) offsets
#define OFF_XL2  (OFF_S + NBUCK * NCHUNK + 8)
#define OFF_XR2  (OFF_XL2 + N_NODES * NCLS)

__device__ __forceinline__ float bload16(unsigned short u) {
    return __uint_as_float(((unsigned)u) << 16);
}

// lrelu(v) = 0.6v + 0.4|v|
__device__ __forceinline__ float lrelu(float v) {
    return fmaf(0.4f, fabsf(v), 0.6f * v);
}

__device__ __forceinline__ void unpack8(uint4 q, float* f) {
    f[0] = __uint_as_float(q.x << 16); f[1] = __uint_as_float(q.x & 0xffff0000u);
    f[2] = __uint_as_float(q.y << 16); f[3] = __uint_as_float(q.y & 0xffff0000u);
    f[4] = __uint_as_float(q.z << 16); f[5] = __uint_as_float(q.z & 0xffff0000u);
    f[6] = __uint_as_float(q.w << 16); f[7] = __uint_as_float(q.w & 0xffff0000u);
}

__device__ __forceinline__ unsigned short f2b(float f) {
    __hip_bfloat16 b = __float2bfloat16(f);
    return *(unsigned short*)&b;
}

// wave-uniform dtype sniff: 64 halves of x; bf16 -> ~all plausible, fp32 -> ~58%
__device__ __forceinline__ unsigned detect_flag(const unsigned short* x16, int lane) {
    unsigned short hh = x16[lane];
    unsigned e = (hh >> 7) & 0xFF;
    bool pl = ((hh & 0x7FFF) == 0) || (e >= 100 && e <= 140);
    unsigned long long m = __ballot(pl);
    return (__popcll(m) >= 52) ? 1u : 0u;
}

// ---- fused prep: flag + WT/bcat (layer-1 weights, bf16) + small wb (fp32) ----
#define PREP_WT 49152                       // 256*192
#define PREP_BC (PREP_WT + 256)
#define PREP_TOT (PREP_BC + 776)
__global__ void __launch_bounds__(256) k_prep(
        const unsigned short* __restrict__ x16,
        const void* W1l, const void* b1l, const void* W1r, const void* b1r,
        const void* att1, const void* bias1, const void* W2l, const void* b2l,
        const void* W2r, const void* b2r, const void* att2, const void* bias2,
        unsigned* __restrict__ flagp, unsigned short* __restrict__ wt,
        float* __restrict__ bcat, float* __restrict__ wb) {
    int lane = threadIdx.x & 63;
    unsigned isbf = detect_flag(x16, lane);
    int i = blockIdx.x * 256 + threadIdx.x;
    if (i == 0) *flagp = isbf;
    if (i >= PREP_TOT) return;
    if (i < PREP_WT) {
        int n = i / KP, k = i - n * KP;
        unsigned short v = 0;
        if (k < NFEAT) {
            const void* src = (n < HID) ? W1l : W1r;
            size_t off = (size_t)k * HID + (n & (HID - 1));
            v = isbf ? ((const unsigned short*)src)[off]
                     : f2b(((const float*)src)[off]);
        }
        wt[i] = v;
    } else if (i < PREP_BC) {
        int n = i - PREP_WT;
        const void* src = (n < HID) ? b1l : b1r;
        int off = n & (HID - 1);
        bcat[n] = isbf ? bload16(((const unsigned short*)src)[off])
                       : ((const float*)src)[off];
    } else {
        int j = i - PREP_BC;
        const void* src; int off; int dst;
        if      (j < 128) { src = att1;  off = j;       dst = WO_ATT1 + j; }
        else if (j < 256) { src = bias1; off = j - 128; dst = WO_BIAS1 + (j - 128); }
        else if (j < 512) { src = W2l;   off = j - 256; dst = WO_W2L + (j - 256); }
        else if (j < 514) { src = b2l;   off = j - 512; dst = WO_B2L + (j - 512); }
        else if (j < 770) { src = W2r;   off = j - 514; dst = WO_W2R + (j - 514); }
        else if (j < 772) { src = b2r;   off = j - 770; dst = WO_B2R + (j - 770); }
        else if (j < 774) { src = att2;  off = j - 772; dst = WO_ATT2 + (j - 772); }
        else              { src = bias2; off = j - 774; dst = WO_BIAS2 + (j - 774); }
        wb[dst] = isbf ? bload16(((const unsigned short*)src)[off])
                       : ((const float*)src)[off];
    }
}

// ================= CSR build: two-level counting sort =================
__global__ void __launch_bounds__(256) k_pa_hist(const int* __restrict__ edst,
                                                 int* __restrict__ bh) {
    __shared__ int hist[NBUCK];
    for (int i = threadIdx.x; i < NBUCK; i += 256) hist[i] = 0;
    __syncthreads();
    int base = blockIdx.x * CHUNK;
    for (int i = threadIdx.x; i < CHUNK; i += 256) {
        int e = base + i;
        if (e >= ETOT) break;
        int d = (e < N_EDGES) ? edst[e] : (e - N_EDGES);
        atomicAdd(&hist[d >> 8], 1);
    }
    __syncthreads();
    for (int b = threadIdx.x; b < NBUCK; b += 256)
        bh[b * NCHUNK + blockIdx.x] = hist[b];
}

__global__ void __launch_bounds__(512) k_pa_scan(int* __restrict__ S,
                                                 int* __restrict__ rowptr) {
    __shared__ int lds[512];
    const int TOT = NBUCK * NCHUNK;
    const int per = (TOT + 511) / 512;
    int t = threadIdx.x;
    int beg = t * per;
    int sum = 0;
    for (int k = 0; k < per; k++) {
        int i = beg + k;
        if (i < TOT) sum += S[i];
    }
    lds[t] = sum;
    __syncthreads();
    for (int off = 1; off < 512; off <<= 1) {
        int v = lds[t];
        if (t >= off) v += lds[t - off];
        __syncthreads();
        lds[t] = v;
        __syncthreads();
    }
    int carry = (t == 0) ? 0 : lds[t - 1];
    for (int k = 0; k < per; k++) {
        int i = beg + k;
        if (i < TOT) {
            int v = S[i];
            S[i] = carry;
            carry += v;
        }
    }
    if (t == 0) rowptr[N_NODES] = ETOT;
}

__global__ void __launch_bounds__(256) k_pa_scatter(const int* __restrict__ esrc,
                                                    const int* __restrict__ edst,
                                                    const int* __restrict__ S,
                                                    int2* __restrict__ pairs) {
    __shared__ int cur[NBUCK];
    for (int i = threadIdx.x; i < NBUCK; i += 256)
        cur[i] = S[i * NCHUNK + blockIdx.x];
    __syncthreads();
    int base = blockIdx.x * CHUNK;
    for (int i = threadIdx.x; i < CHUNK; i += 256) {
        int e = base + i;
        if (e >= ETOT) break;
        int s = (e < N_EDGES) ? esrc[e] : (e - N_EDGES);
        int d = (e < N_EDGES) ? edst[e] : (e - N_EDGES);
        int p = atomicAdd(&cur[d >> 8], 1);
        pairs[p] = make_int2(s, d);
    }
}

__global__ void __launch_bounds__(256) k_bsort(const int* __restrict__ S,
                                               const int2* __restrict__ pairs,
                                               int* __restrict__ rowptr,
                                               int* __restrict__ csr) {
    __shared__ int hist[256];
    __shared__ int cur[256];
    int b = blockIdx.x, t = threadIdx.x;
    int beg = S[b * NCHUNK];
    int end = (b == NBUCK - 1) ? ETOT : S[(b + 1) * NCHUNK];
    hist[t] = 0;
    __syncthreads();
    for (int j = beg + t; j < end; j += 256)
        atomicAdd(&hist[pairs[j].y & 255], 1);
    __syncthreads();
    for (int off = 1; off < 256; off <<= 1) {
        int v = hist[t];
        if (t >= off) v += hist[t - off];
        __syncthreads();
        hist[t] = v;
        __syncthreads();
    }
    int excl = (t == 0) ? 0 : hist[t - 1];
    int node = b * 256 + t;
    if (node < N_NODES) rowptr[node] = beg + excl;
    cur[t] = beg + excl;
    __syncthreads();
    for (int j = beg + t; j < end; j += 256) {
        int2 pr = pairs[j];
        int p = atomicAdd(&cur[pr.y & 255], 1);
        csr[p] = pr.x;
    }
}

// ================= layer-1 GEMM via bf16 MFMA (C^T trick for coalesced C) ====
// Operand swap: mfma(wfrag, xfrag) gives each lane 4 CONSECUTIVE output
// columns of one node row -> one packed 8-B store per tile.
// x staging: the block's 64 rows are one contiguous 16-B-aligned flat span
// (64*165 halves); load vectorized, scatter to LDS per-half (divmod 165).
#define XS_STRIDE 200
__global__ void __launch_bounds__(256) k_gemm1_mfma(
        const void* __restrict__ x,
        const unsigned* __restrict__ flagp,
        const unsigned short* __restrict__ wt,
        const float* __restrict__ bcat,
        __hip_bfloat16* __restrict__ xlb,
        __hip_bfloat16* __restrict__ xrb) {
    __shared__ unsigned short xs[64 * XS_STRIDE];
    int tid = threadIdx.x;
    int wave = tid >> 6, lane = tid & 63;
    int quad = lane >> 4, li = lane & 15;
    int node0 = blockIdx.x * 64;
    unsigned isbf = *flagp;
    const float* xf = (const float*)x;
    const unsigned short* x16 = (const unsigned short*)x;

    // zero pad cols [165,192)
    for (int i = tid; i < 64 * 27; i += 256) {
        int r = i / 27, c = 165 + (i - r * 27);
        xs[r * XS_STRIDE + c] = 0;
    }
    if (node0 + 64 <= N_NODES) {
        if (isbf) {
            const uint4* src = (const uint4*)(x16 + (size_t)node0 * NFEAT);
            for (int i = tid; i < 1320; i += 256) {   // 1320*8 = 64*165 halves
                uint4 v = src[i];
                int f = i * 8;
                unsigned short hh[8] = {
                    (unsigned short)(v.x & 0xffff), (unsigned short)(v.x >> 16),
                    (unsigned short)(v.y & 0xffff), (unsigned short)(v.y >> 16),
                    (unsigned short)(v.z & 0xffff), (unsigned short)(v.z >> 16),
                    (unsigned short)(v.w & 0xffff), (unsigned short)(v.w >> 16)};
#pragma unroll
                for (int t = 0; t < 8; t++) {
                    int ff = f + t, r = ff / NFEAT, c = ff - r * NFEAT;
                    xs[r * XS_STRIDE + c] = hh[t];
                }
            }
        } else {
            const float4* src = (const float4*)(xf + (size_t)node0 * NFEAT);
            for (int i = tid; i < 2640; i += 256) {   // 2640*4 = 64*165 floats
                float4 v = src[i];
                int f = i * 4;
                unsigned short hh[4] = {f2b(v.x), f2b(v.y), f2b(v.z), f2b(v.w)};
#pragma unroll
                for (int t = 0; t < 4; t++) {
                    int ff = f + t, r = ff / NFEAT, c = ff - r * NFEAT;
                    xs[r * XS_STRIDE + c] = hh[t];
                }
            }
        }
    } else {
        // last partial block: guarded scalar path
        for (int i = tid; i < 64 * NFEAT; i += 256) {
            int r = i / NFEAT, c = i - r * NFEAT;
            int grow = node0 + r;
            unsigned short v = 0;
            if (grow < N_NODES) {
                size_t g = (size_t)grow * NFEAT + c;
                v = isbf ? x16[g] : f2b(xf[g]);
            }
            xs[r * XS_STRIDE + c] = v;
        }
    }

    // W fragments (used as the A operand): lane li holds W^T[col][k]
    bf16x8 wfrag[4][6];
#pragma unroll
    for (int q = 0; q < 4; q++) {
        int n = wave * 64 + q * 16 + li;
#pragma unroll
        for (int kk = 0; kk < 6; kk++)
            wfrag[q][kk] = *(const bf16x8*)&wt[(size_t)n * KP + kk * 32 + quad * 8];
    }
    float4 bv[4];
#pragma unroll
    for (int q = 0; q < 4; q++)
        bv[q] = *(const float4*)&bcat[wave * 64 + q * 16 + quad * 4];
    __syncthreads();

    for (int mt = 0; mt < 4; mt++) {
        bf16x8 xfrag[6];
#pragma unroll
        for (int kk = 0; kk < 6; kk++)
            xfrag[kk] = *(const bf16x8*)&xs[(mt * 16 + li) * XS_STRIDE + kk * 32 + quad * 8];
        int node = node0 + mt * 16 + li;
        __hip_bfloat16* dst = (wave < 2) ? xlb : xrb;
#pragma unroll
        for (int q = 0; q < 4; q++) {
            f32x4 a = {0.f, 0.f, 0.f, 0.f};
#pragma unroll
            for (int kk = 0; kk < 6; kk++)
                a = __builtin_amdgcn_mfma_f32_16x16x32_bf16(wfrag[q][kk], xfrag[kk], a, 0, 0, 0);
            unsigned short s0 = f2b(a[0] + bv[q].x), s1 = f2b(a[1] + bv[q].y);
            unsigned short s2 = f2b(a[2] + bv[q].z), s3 = f2b(a[3] + bv[q].w);
            uint2 val = { (unsigned)s0 | ((unsigned)s1 << 16),
                          (unsigned)s2 | ((unsigned)s3 << 16) };
            int col = (wave & 1) * 64 + q * 16 + quad * 4;
            *(uint2*)&dst[(size_t)node * HID + col] = val;
        }
    }
}

// ================= fused layer-1 attention + layer-2 GEMM epilogue ==========
__global__ void __launch_bounds__(256) k_gat1(const int* __restrict__ rowptr,
                                              const int* __restrict__ csr,
                                              const __hip_bfloat16* __restrict__ xlb,
                                              const __hip_bfloat16* __restrict__ xrb,
                                              const float* __restrict__ wb,
                                              float* __restrict__ xl2,
                                              float* __restrict__ xr2) {
    int wave = threadIdx.x >> 6, lane = threadIdx.x & 63;
    int d = blockIdx.x * 4 + wave;
    if (d >= N_NODES) return;
    int sub = lane >> 4, li = lane & 15;

    uint4 qr = ((const uint4*)(xrb + (size_t)d * HID))[li];
    float xrv[8]; unpack8(qr, xrv);
    const float* att = wb + WO_ATT1;
    float atv[8];
    {
        float4 t0 = ((const float4*)att)[li * 2];
        float4 t1 = ((const float4*)att)[li * 2 + 1];
        atv[0] = t0.x; atv[1] = t0.y; atv[2] = t0.z; atv[3] = t0.w;
        atv[4] = t1.x; atv[5] = t1.y; atv[6] = t1.z; atv[7] = t1.w;
    }
    int beg = rowptr[d], end = rowptr[d + 1];
    int iters = (end - beg + 3) >> 2;
    float l = 0.f, o[8];
#pragma unroll
    for (int t = 0; t < 8; t++) o[t] = 0.f;

    int j = beg + sub;
    bool valid = j < end;
    int s = valid ? csr[j] : 0;
    uint4 q = *(const uint4*)(xlb + (size_t)s * HID + li * 8);

    for (int it = 0; it < iters; it++) {
        float c[8]; unpack8(q, c);
        bool v = valid;
        j += 4;
        valid = j < end;
        int sn = valid ? csr[j] : 0;
        q = *(const uint4*)(xlb + (size_t)sn * HID + li * 8);

        float p = 0.f;
#pragma unroll
        for (int t = 0; t < 8; t++) p = fmaf(atv[t], lrelu(c[t] + xrv[t]), p);
        p += __shfl_xor(p, 1);
        p += __shfl_xor(p, 2);
        p += __shfl_xor(p, 4);
        p += __shfl_xor(p, 8);
        float a = v ? __expf(p) : 0.f;
        l += a;
#pragma unroll
        for (int t = 0; t < 8; t++) o[t] = fmaf(a, c[t], o[t]);
    }
    // merge the 4 subgroups
    l += __shfl_xor(l, 16);
    l += __shfl_xor(l, 32);
#pragma unroll
    for (int t = 0; t < 8; t++) {
        o[t] += __shfl_xor(o[t], 16);
        o[t] += __shfl_xor(o[t], 32);
    }
    // ---- epilogue (loads only touched here, after the hot loop) ----
    float inv = 1.f / l;  // self-loop guarantees l > 0
    const float* bias1 = wb + WO_BIAS1;
    float4 b0 = ((const float4*)bias1)[li * 2];
    float4 b1 = ((const float4*)bias1)[li * 2 + 1];
    float hv[8];
    hv[0] = fmaxf(fmaf(o[0], inv, b0.x), 0.f);
    hv[1] = fmaxf(fmaf(o[1], inv, b0.y), 0.f);
    hv[2] = fmaxf(fmaf(o[2], inv, b0.z), 0.f);
    hv[3] = fmaxf(fmaf(o[3], inv, b0.w), 0.f);
    hv[4] = fmaxf(fmaf(o[4], inv, b1.x), 0.f);
    hv[5] = fmaxf(fmaf(o[5], inv, b1.y), 0.f);
    hv[6] = fmaxf(fmaf(o[6], inv, b1.z), 0.f);
    hv[7] = fmaxf(fmaf(o[7], inv, b1.w), 0.f);
    const float* wsel = (sub < 2) ? (wb + WO_W2L) : (wb + WO_W2R);
    int cls = sub & 1;
    float pr = 0.f;
#pragma unroll
    for (int t = 0; t < 8; t++) pr = fmaf(hv[t], wsel[(li * 8 + t) * 2 + cls], pr);
    pr += __shfl_xor(pr, 1);
    pr += __shfl_xor(pr, 2);
    pr += __shfl_xor(pr, 4);
    pr += __shfl_xor(pr, 8);
    if (li == 0) {
        float outb = (sub < 2) ? wb[WO_B2L + cls] : wb[WO_B2R + cls];
        float* basep = (sub < 2) ? xl2 : xr2;
        basep[2 * d + cls] = pr + outb;
    }
}

// ================= fused layer-2 attention: thread per dst node ==============
__global__ void __launch_bounds__(256) k_gat2(const int* __restrict__ rowptr,
                                              const int* __restrict__ csr,
                                              const float* __restrict__ xl2,
                                              const float* __restrict__ xr2,
                                              const float* __restrict__ wb,
                                              const unsigned* __restrict__ flag,
                                              void* __restrict__ dout) {
    int d = blockIdx.x * 256 + threadIdx.x;
    if (d >= N_NODES) return;
    float xr0 = xr2[d * 2 + 0], xr1 = xr2[d * 2 + 1];
    float at0 = wb[WO_ATT2], at1 = wb[WO_ATT2 + 1];
    int beg = rowptr[d], end = rowptr[d + 1];
    float l = 0.f, o0 = 0.f, o1 = 0.f;
    for (int j = beg; j < end; j++) {
        int s = csr[j];
        float b0 = xl2[s * 2 + 0], b1 = xl2[s * 2 + 1];
        float p = at0 * lrelu(b0 + xr0) + at1 * lrelu(b1 + xr1);
        float a = __expf(p);
        l += a;
        o0 = fmaf(a, b0, o0);
        o1 = fmaf(a, b1, o1);
    }
    float inv = 1.f / l;
    float v0 = fmaf(o0, inv, wb[WO_BIAS2 + 0]);
    float v1 = fmaf(o1, inv, wb[WO_BIAS2 + 1]);
    if (*flag) {
        ((__hip_bfloat16*)dout)[d * 2 + 0] = __float2bfloat16(v0);
        ((__hip_bfloat16*)dout)[d * 2 + 1] = __float2bfloat16(v1);
    } else {
        ((float*)dout)[d * 2 + 0] = v0;
        ((float*)dout)[d * 2 + 1] = v1;
    }
}

extern "C" void kernel_launch(void* const* d_in, const int* in_sizes, int n_in,
                              void* d_out, int out_size, void* d_ws, size_t ws_size,
                              hipStream_t stream) {
    char* w = (char*)d_ws;
    unsigned* flag = (unsigned*)(w + (size_t)OFF_FLAG * 4);
    float* wb = (float*)(w + (size_t)OFF_W * 4);
    unsigned short* wt = (unsigned short*)(w + (size_t)OFF_WT * 4);
    float* bcat = (float*)(w + (size_t)OFF_BCAT * 4);
    __hip_bfloat16* xlb = (__hip_bfloat16*)(w + (size_t)OFF_XLB * 4);
    __hip_bfloat16* xrb = (__hip_bfloat16*)(w + (size_t)OFF_XRB * 4);
    int2* pairs = (int2*)(w + (size_t)OFF_PAIRS * 4);
    int* csr = (int*)(w + (size_t)OFF_CSR * 4);
    int* rowptr = (int*)(w + (size_t)OFF_ROWPTR * 4);
    int* S = (int*)(w + (size_t)OFF_S * 4);
    float* xl2 = (float*)(w + (size_t)OFF_XL2 * 4);
    float* xr2 = (float*)(w + (size_t)OFF_XR2 * 4);
    const int* esrc = (const int*)d_in[1];
    const int* edst = (const int*)d_in[2];

    k_prep<<<(PREP_TOT + 255) / 256, 256, 0, stream>>>(
        (const unsigned short*)d_in[0],
        d_in[3], d_in[4], d_in[5], d_in[6], d_in[7], d_in[8],
        d_in[9], d_in[10], d_in[11], d_in[12], d_in[13], d_in[14],
        flag, wt, bcat, wb);

    // ---- CSR build FIRST (so gemm1's xlb/xrb output is L2-warm for gat1) ----
    k_pa_hist<<<NCHUNK, 256, 0, stream>>>(edst, S);
    k_pa_scan<<<1, 512, 0, stream>>>(S, rowptr);
    k_pa_scatter<<<NCHUNK, 256, 0, stream>>>(esrc, edst, S, pairs);
    k_bsort<<<NBUCK, 256, 0, stream>>>(S, pairs, rowptr, csr);

    // ---- layer-1 GEMM (vectorized x staging; C^T coalesced stores) ----
    k_gemm1_mfma<<<NPAD / 64, 256, 0, stream>>>(d_in[0], flag, wt, bcat, xlb, xrb);

    // ---- fused layer-1 attention + layer-2 projection ----
    k_gat1<<<(N_NODES + 3) / 4, 256, 0, stream>>>(rowptr, csr, xlb, xrb, wb,
                                                  xl2, xr2);

    // ---- layer-2 attention + output ----
    k_gat2<<<(N_NODES + 255) / 256, 256, 0, stream>>>(rowptr, csr, xl2, xr2,
                                                      wb, flag, d_out);
}

// Round 9
// 458.541 us; speedup vs baseline: 1.2085x; 1.0224x over previous
//
#include <hip/hip_runtime.h>
#include <hip/hip_bf16.h>

#define N_NODES 100000
#define NPAD 100032                         // 64-row-aligned node count
#define N_EDGES 1600000
#define ETOT (N_EDGES + N_NODES)
#define NFEAT 165
#define KP 192                              // K padded to 32-multiple
#define HID 128
#define NCLS 2
#define NEG 0.2f

// CSR radix-build parameters
#define NBUCK 391                           // ceil(N_NODES/256); bucket = dst >> 8
#define CHUNK 16384
#define NCHUNK 104                          // ceil(ETOT/CHUNK)

typedef short bf16x8 __attribute__((ext_vector_type(8)));
typedef float f32x4 __attribute__((ext_vector_type(4)));

// ---- workspace layout (units of 4 bytes) ----
#define OFF_FLAG 0
#define OFF_W 16
// weight sub-offsets (within wb = ws + OFF_W)
#define WO_ATT1 42496
#define WO_BIAS1 42624
#define WO_W2L 42752
#define WO_B2L 43008
#define WO_W2R 43010
#define WO_B2R 43266
#define WO_ATT2 43268
#define WO_BIAS2 43270

#define OFF_XB   43392
#define OFF_WT   (OFF_XB + NPAD * KP / 2)   // bf16 WT [256][192]
#define OFF_BCAT (OFF_WT + 256 * KP / 2)    // fp32 bias concat [256]
#define OFF_XLB  (OFF_BCAT + 256)           // bf16 xl rows [NPAD][128]
#define OFF_XRB  (OFF_XLB + NPAD * HID / 2) // bf16 xr rows
#define OFF_PAIRS (OFF_XRB + NPAD * HID / 2) // int2 pairs[ETOT]
#define OFF_CSR  (OFF_PAIRS + 2 * ETOT)     // csr_src[ETOT]
#define OFF_ROWPTR (OFF_CSR + ETOT)         // rowptr[N_NODES+1]
#define OFF_S    (OFF_ROWPTR + N_NODES + 8) // per-(bucket,chunk) offsets
#define OFF_XL2  (OFF_S + NBUCK * NCHUNK + 8)
#define OFF_XR2  (OFF_XL2 + N_NODES * NCLS)
#define OFF_H    (OFF_XR2 + N_NODES * NCLS) // fp32 h [N][128]

__device__ __forceinline__ float bload16(unsigned short u) {
    return __uint_as_float(((unsigned)u) << 16);
}

// lrelu(v) = 0.6v + 0.4|v|
__device__ __forceinline__ float lrelu(float v) {
    return fmaf(0.4f, fabsf(v), 0.6f * v);
}

__device__ __forceinline__ void unpack8(uint4 q, float* f) {
    f[0] = __uint_as_float(q.x << 16); f[1] = __uint_as_float(q.x & 0xffff0000u);
    f[2] = __uint_as_float(q.y << 16); f[3] = __uint_as_float(q.y & 0xffff0000u);
    f[4] = __uint_as_float(q.z << 16); f[5] = __uint_as_float(q.z & 0xffff0000u);
    f[6] = __uint_as_float(q.w << 16); f[7] = __uint_as_float(q.w & 0xffff0000u);
}

__device__ __forceinline__ unsigned short f2b(float f) {
    __hip_bfloat16 b = __float2bfloat16(f);
    return *(unsigned short*)&b;
}

// wave-uniform dtype sniff: 64 halves of x; bf16 -> ~all plausible, fp32 -> ~58%
__device__ __forceinline__ unsigned detect_flag(const unsigned short* x16, int lane) {
    unsigned short hh = x16[lane];
    unsigned e = (hh >> 7) & 0xFF;
    bool pl = ((hh & 0x7FFF) == 0) || (e >= 100 && e <= 140);
    unsigned long long m = __ballot(pl);
    return (__popcll(m) >= 52) ? 1u : 0u;
}

// ---- fused prep: flag + WT/bcat (layer-1 weights, bf16) + small wb (fp32) ----
#define PREP_WT 49152                       // 256*192
#define PREP_BC (PREP_WT + 256)
#define PREP_TOT (PREP_BC + 776)
__global__ void __launch_bounds__(256) k_prep(
        const unsigned short* __restrict__ x16,
        const void* W1l, const void* b1l, const void* W1r, const void* b1r,
        const void* att1, const void* bias1, const void* W2l, const void* b2l,
        const void* W2r, const void* b2r, const void* att2, const void* bias2,
        unsigned* __restrict__ flagp, unsigned short* __restrict__ wt,
        float* __restrict__ bcat, float* __restrict__ wb) {
    int lane = threadIdx.x & 63;
    unsigned isbf = detect_flag(x16, lane);
    int i = blockIdx.x * 256 + threadIdx.x;
    if (i == 0) *flagp = isbf;
    if (i >= PREP_TOT) return;
    if (i < PREP_WT) {
        int n = i / KP, k = i - n * KP;
        unsigned short v = 0;
        if (k < NFEAT) {
            const void* src = (n < HID) ? W1l : W1r;
            size_t off = (size_t)k * HID + (n & (HID - 1));
            v = isbf ? ((const unsigned short*)src)[off]
                     : f2b(((const float*)src)[off]);
        }
        wt[i] = v;
    } else if (i < PREP_BC) {
        int n = i - PREP_WT;
        const void* src = (n < HID) ? b1l : b1r;
        int off = n & (HID - 1);
        bcat[n] = isbf ? bload16(((const unsigned short*)src)[off])
                       : ((const float*)src)[off];
    } else {
        int j = i - PREP_BC;
        const void* src; int off; int dst;
        if      (j < 128) { src = att1;  off = j;       dst = WO_ATT1 + j; }
        else if (j < 256) { src = bias1; off = j - 128; dst = WO_BIAS1 + (j - 128); }
        else if (j < 512) { src = W2l;   off = j - 256; dst = WO_W2L + (j - 256); }
        else if (j < 514) { src = b2l;   off = j - 512; dst = WO_B2L + (j - 512); }
        else if (j < 770) { src = W2r;   off = j - 514; dst = WO_W2R + (j - 514); }
        else if (j < 772) { src = b2r;   off = j - 770; dst = WO_B2R + (j - 770); }
        else if (j < 774) { src = att2;  off = j - 772; dst = WO_ATT2 + (j - 772); }
        else              { src = bias2; off = j - 774; dst = WO_BIAS2 + (j - 774); }
        wb[dst] = isbf ? bload16(((const unsigned short*)src)[off])
                       : ((const float*)src)[off];
    }
}

// ================= CSR build: two-level counting sort =================
__global__ void __launch_bounds__(256) k_pa_hist(const int* __restrict__ edst,
                                                 int* __restrict__ bh) {
    __shared__ int hist[NBUCK];
    for (int i = threadIdx.x; i < NBUCK; i += 256) hist[i] = 0;
    __syncthreads();
    int base = blockIdx.x * CHUNK;
    for (int i = threadIdx.x; i < CHUNK; i += 256) {
        int e = base + i;
        if (e >= ETOT) break;
        int d = (e < N_EDGES) ? edst[e] : (e - N_EDGES);
        atomicAdd(&hist[d >> 8], 1);
    }
    __syncthreads();
    for (int b = threadIdx.x; b < NBUCK; b += 256)
        bh[b * NCHUNK + blockIdx.x] = hist[b];
}

__global__ void __launch_bounds__(512) k_pa_scan(int* __restrict__ S,
                                                 int* __restrict__ rowptr) {
    __shared__ int lds[512];
    const int TOT = NBUCK * NCHUNK;
    const int per = (TOT + 511) / 512;
    int t = threadIdx.x;
    int beg = t * per;
    int sum = 0;
    for (int k = 0; k < per; k++) {
        int i = beg + k;
        if (i < TOT) sum += S[i];
    }
    lds[t] = sum;
    __syncthreads();
    for (int off = 1; off < 512; off <<= 1) {
        int v = lds[t];
        if (t >= off) v += lds[t - off];
        __syncthreads();
        lds[t] = v;
        __syncthreads();
    }
    int carry = (t == 0) ? 0 : lds[t - 1];
    for (int k = 0; k < per; k++) {
        int i = beg + k;
        if (i < TOT) {
            int v = S[i];
            S[i] = carry;
            carry += v;
        }
    }
    if (t == 0) rowptr[N_NODES] = ETOT;
}

__global__ void __launch_bounds__(256) k_pa_scatter(const int* __restrict__ esrc,
                                                    const int* __restrict__ edst,
                                                    const int* __restrict__ S,
                                                    int2* __restrict__ pairs) {
    __shared__ int cur[NBUCK];
    for (int i = threadIdx.x; i < NBUCK; i += 256)
        cur[i] = S[i * NCHUNK + blockIdx.x];
    __syncthreads();
    int base = blockIdx.x * CHUNK;
    for (int i = threadIdx.x; i < CHUNK; i += 256) {
        int e = base + i;
        if (e >= ETOT) break;
        int s = (e < N_EDGES) ? esrc[e] : (e - N_EDGES);
        int d = (e < N_EDGES) ? edst[e] : (e - N_EDGES);
        int p = atomicAdd(&cur[d >> 8], 1);
        pairs[p] = make_int2(s, d);
    }
}

__global__ void __launch_bounds__(256) k_bsort(const int* __restrict__ S,
                                               const int2* __restrict__ pairs,
                                               int* __restrict__ rowptr,
                                               int* __restrict__ csr) {
    __shared__ int hist[256];
    __shared__ int cur[256];
    int b = blockIdx.x, t = threadIdx.x;
    int beg = S[b * NCHUNK];
    int end = (b == NBUCK - 1) ? ETOT : S[(b + 1) * NCHUNK];
    hist[t] = 0;
    __syncthreads();
    for (int j = beg + t; j < end; j += 256)
        atomicAdd(&hist[pairs[j].y & 255], 1);
    __syncthreads();
    for (int off = 1; off < 256; off <<= 1) {
        int v = hist[t];
        if (t >= off) v += hist[t - off];
        __syncthreads();
        hist[t] = v;
        __syncthreads();
    }
    int excl = (t == 0) ? 0 : hist[t - 1];
    int node = b * 256 + t;
    if (node < N_NODES) rowptr[node] = beg + excl;
    cur[t] = beg + excl;
    __syncthreads();
    for (int j = beg + t; j < end; j += 256) {
        int2 pr = pairs[j];
        int p = atomicAdd(&cur[pr.y & 255], 1);
        csr[p] = pr.x;
    }
}

// ================= layer-1 GEMM via bf16 MFMA (C^T trick for coalesced C) ====
#define XS_STRIDE 200
__global__ void __launch_bounds__(256) k_gemm1_mfma(
        const void* __restrict__ x,
        const unsigned* __restrict__ flagp,
        const unsigned short* __restrict__ wt,
        const float* __restrict__ bcat,
        __hip_bfloat16* __restrict__ xlb,
        __hip_bfloat16* __restrict__ xrb) {
    __shared__ unsigned short xs[64 * XS_STRIDE];
    int tid = threadIdx.x;
    int wave = tid >> 6, lane = tid & 63;
    int quad = lane >> 4, li = lane & 15;
    int node0 = blockIdx.x * 64;
    unsigned isbf = *flagp;
    const float* xf = (const float*)x;
    const unsigned short* x16 = (const unsigned short*)x;

    // zero pad cols [165,192)
    for (int i = tid; i < 64 * 27; i += 256) {
        int r = i / 27, c = 165 + (i - r * 27);
        xs[r * XS_STRIDE + c] = 0;
    }
    if (node0 + 64 <= N_NODES) {
        if (isbf) {
            const uint4* src = (const uint4*)(x16 + (size_t)node0 * NFEAT);
            for (int i = tid; i < 1320; i += 256) {   // 1320*8 = 64*165 halves
                uint4 v = src[i];
                int f = i * 8;
                unsigned short hh[8] = {
                    (unsigned short)(v.x & 0xffff), (unsigned short)(v.x >> 16),
                    (unsigned short)(v.y & 0xffff), (unsigned short)(v.y >> 16),
                    (unsigned short)(v.z & 0xffff), (unsigned short)(v.z >> 16),
                    (unsigned short)(v.w & 0xffff), (unsigned short)(v.w >> 16)};
#pragma unroll
                for (int t = 0; t < 8; t++) {
                    int ff = f + t, r = ff / NFEAT, c = ff - r * NFEAT;
                    xs[r * XS_STRIDE + c] = hh[t];
                }
            }
        } else {
            const float4* src = (const float4*)(xf + (size_t)node0 * NFEAT);
            for (int i = tid; i < 2640; i += 256) {   // 2640*4 = 64*165 floats
                float4 v = src[i];
                int f = i * 4;
                unsigned short hh[4] = {f2b(v.x), f2b(v.y), f2b(v.z), f2b(v.w)};
#pragma unroll
                for (int t = 0; t < 4; t++) {
                    int ff = f + t, r = ff / NFEAT, c = ff - r * NFEAT;
                    xs[r * XS_STRIDE + c] = hh[t];
                }
            }
        }
    } else {
        for (int i = tid; i < 64 * NFEAT; i += 256) {
            int r = i / NFEAT, c = i - r * NFEAT;
            int grow = node0 + r;
            unsigned short v = 0;
            if (grow < N_NODES) {
                size_t g = (size_t)grow * NFEAT + c;
                v = isbf ? x16[g] : f2b(xf[g]);
            }
            xs[r * XS_STRIDE + c] = v;
        }
    }

    bf16x8 wfrag[4][6];
#pragma unroll
    for (int q = 0; q < 4; q++) {
        int n = wave * 64 + q * 16 + li;
#pragma unroll
        for (int kk = 0; kk < 6; kk++)
            wfrag[q][kk] = *(const bf16x8*)&wt[(size_t)n * KP + kk * 32 + quad * 8];
    }
    float4 bv[4];
#pragma unroll
    for (int q = 0; q < 4; q++)
        bv[q] = *(const float4*)&bcat[wave * 64 + q * 16 + quad * 4];
    __syncthreads();

    for (int mt = 0; mt < 4; mt++) {
        bf16x8 xfrag[6];
#pragma unroll
        for (int kk = 0; kk < 6; kk++)
            xfrag[kk] = *(const bf16x8*)&xs[(mt * 16 + li) * XS_STRIDE + kk * 32 + quad * 8];
        int node = node0 + mt * 16 + li;
        __hip_bfloat16* dst = (wave < 2) ? xlb : xrb;
#pragma unroll
        for (int q = 0; q < 4; q++) {
            f32x4 a = {0.f, 0.f, 0.f, 0.f};
#pragma unroll
            for (int kk = 0; kk < 6; kk++)
                a = __builtin_amdgcn_mfma_f32_16x16x32_bf16(wfrag[q][kk], xfrag[kk], a, 0, 0, 0);
            unsigned short s0 = f2b(a[0] + bv[q].x), s1 = f2b(a[1] + bv[q].y);
            unsigned short s2 = f2b(a[2] + bv[q].z), s3 = f2b(a[3] + bv[q].w);
            uint2 val = { (unsigned)s0 | ((unsigned)s1 << 16),
                          (unsigned)s2 | ((unsigned)s3 << 16) };
            int col = (wave & 1) * 64 + q * 16 + quad * 4;
            *(uint2*)&dst[(size_t)node * HID + col] = val;
        }
    }
}

// ================= fused layer-1 attention (verbatim R4 measured-fast form) ==
__global__ void __launch_bounds__(256) k_gat1(const int* __restrict__ rowptr,
                                              const int* __restrict__ csr,
                                              const __hip_bfloat16* __restrict__ xlb,
                                              const __hip_bfloat16* __restrict__ xrb,
                                              const float* __restrict__ att,
                                              const float* __restrict__ bias,
                                              float* __restrict__ h) {
    int wave = threadIdx.x >> 6, lane = threadIdx.x & 63;
    int d = blockIdx.x * 4 + wave;
    if (d >= N_NODES) return;
    int sub = lane >> 4, li = lane & 15;

    uint4 qr = ((const uint4*)(xrb + (size_t)d * HID))[li];
    float xrv[8]; unpack8(qr, xrv);
    float atv[8];
    {
        float4 t0 = ((const float4*)att)[li * 2];
        float4 t1 = ((const float4*)att)[li * 2 + 1];
        atv[0] = t0.x; atv[1] = t0.y; atv[2] = t0.z; atv[3] = t0.w;
        atv[4] = t1.x; atv[5] = t1.y; atv[6] = t1.z; atv[7] = t1.w;
    }
    int beg = rowptr[d], end = rowptr[d + 1];
    int iters = (end - beg + 3) >> 2;
    float l = 0.f, o[8];
#pragma unroll
    for (int t = 0; t < 8; t++) o[t] = 0.f;

    int j = beg + sub;
    bool valid = j < end;
    int s = valid ? csr[j] : 0;
    uint4 q = *(const uint4*)(xlb + (size_t)s * HID + li * 8);

    for (int it = 0; it < iters; it++) {
        float c[8]; unpack8(q, c);
        bool v = valid;
        j += 4;
        valid = j < end;
        int sn = valid ? csr[j] : 0;
        q = *(const uint4*)(xlb + (size_t)sn * HID + li * 8);

        float p = 0.f;
#pragma unroll
        for (int t = 0; t < 8; t++) p = fmaf(atv[t], lrelu(c[t] + xrv[t]), p);
        p += __shfl_xor(p, 1);
        p += __shfl_xor(p, 2);
        p += __shfl_xor(p, 4);
        p += __shfl_xor(p, 8);
        float a = v ? __expf(p) : 0.f;
        l += a;
#pragma unroll
        for (int t = 0; t < 8; t++) o[t] = fmaf(a, c[t], o[t]);
    }
    // merge the 4 subgroups
    l += __shfl_xor(l, 16);
    l += __shfl_xor(l, 32);
#pragma unroll
    for (int t = 0; t < 8; t++) {
        o[t] += __shfl_xor(o[t], 16);
        o[t] += __shfl_xor(o[t], 32);
    }
    if (sub == 0) {
        float inv = 1.f / l;  // self-loop guarantees l > 0
        float4 bv0 = ((const float4*)bias)[li * 2];
        float4 bv1 = ((const float4*)bias)[li * 2 + 1];
        float4 r0, r1;
        r0.x = fmaf(o[0], inv, bv0.x); r0.y = fmaf(o[1], inv, bv0.y);
        r0.z = fmaf(o[2], inv, bv0.z); r0.w = fmaf(o[3], inv, bv0.w);
        r1.x = fmaf(o[4], inv, bv1.x); r1.y = fmaf(o[5], inv, bv1.y);
        r1.z = fmaf(o[6], inv, bv1.z); r1.w = fmaf(o[7], inv, bv1.w);
        r0.x = fmaxf(r0.x, 0.f); r0.y = fmaxf(r0.y, 0.f);
        r0.z = fmaxf(r0.z, 0.f); r0.w = fmaxf(r0.w, 0.f);
        r1.x = fmaxf(r1.x, 0.f); r1.y = fmaxf(r1.y, 0.f);
        r1.z = fmaxf(r1.z, 0.f); r1.w = fmaxf(r1.w, 0.f);
        float4* hp = (float4*)(h + (size_t)d * HID + li * 8);
        hp[0] = r0;
        hp[1] = r1;
    }
}

// ================= layer-2 GEMMs: wave per node, shuffle K-reduce ============
__global__ void __launch_bounds__(256) k_gemm2(const float* __restrict__ h,
                                               const float* __restrict__ wb,
                                               float* __restrict__ xl2, float* __restrict__ xr2) {
    const float* W2l = wb + WO_W2L;
    const float* b2l = wb + WO_B2L;
    const float* W2r = wb + WO_W2R;
    const float* b2r = wb + WO_B2R;
    int wave = threadIdx.x >> 6, lane = threadIdx.x & 63;
    int node = blockIdx.x * 4 + wave;
    if (node >= N_NODES) return;
    const float* hr = h + (size_t)node * HID;
    float h0 = hr[lane], h1 = hr[lane + 64];
    float al0 = h0 * W2l[lane * 2 + 0] + h1 * W2l[(lane + 64) * 2 + 0];
    float al1 = h0 * W2l[lane * 2 + 1] + h1 * W2l[(lane + 64) * 2 + 1];
    float ar0 = h0 * W2r[lane * 2 + 0] + h1 * W2r[(lane + 64) * 2 + 0];
    float ar1 = h0 * W2r[lane * 2 + 1] + h1 * W2r[(lane + 64) * 2 + 1];
#pragma unroll
    for (int off = 32; off > 0; off >>= 1) {
        al0 += __shfl_down(al0, off);
        al1 += __shfl_down(al1, off);
        ar0 += __shfl_down(ar0, off);
        ar1 += __shfl_down(ar1, off);
    }
    if (lane == 0) {
        xl2[node * 2 + 0] = al0 + b2l[0];
        xl2[node * 2 + 1] = al1 + b2l[1];
        xr2[node * 2 + 0] = ar0 + b2r[0];
        xr2[node * 2 + 1] = ar1 + b2r[1];
    }
}

// ================= fused layer-2 attention: thread per dst node ==============
__global__ void __launch_bounds__(256) k_gat2(const int* __restrict__ rowptr,
                                              const int* __restrict__ csr,
                                              const float* __restrict__ xl2,
                                              const float* __restrict__ xr2,
                                              const float* __restrict__ wb,
                                              const unsigned* __restrict__ flag,
                                              void* __restrict__ dout) {
    int d = blockIdx.x * 256 + threadIdx.x;
    if (d >= N_NODES) return;
    float xr0 = xr2[d * 2 + 0], xr1 = xr2[d * 2 + 1];
    float at0 = wb[WO_ATT2], at1 = wb[WO_ATT2 + 1];
    int beg = rowptr[d], end = rowptr[d + 1];
    float l = 0.f, o0 = 0.f, o1 = 0.f;
    for (int j = beg; j < end; j++) {
        int s = csr[j];
        float b0 = xl2[s * 2 + 0], b1 = xl2[s * 2 + 1];
        float p = at0 * lrelu(b0 + xr0) + at1 * lrelu(b1 + xr1);
        float a = __expf(p);
        l += a;
        o0 = fmaf(a, b0, o0);
        o1 = fmaf(a, b1, o1);
    }
    float inv = 1.f / l;
    float v0 = fmaf(o0, inv, wb[WO_BIAS2 + 0]);
    float v1 = fmaf(o1, inv, wb[WO_BIAS2 + 1]);
    if (*flag) {
        ((__hip_bfloat16*)dout)[d * 2 + 0] = __float2bfloat16(v0);
        ((__hip_bfloat16*)dout)[d * 2 + 1] = __float2bfloat16(v1);
    } else {
        ((float*)dout)[d * 2 + 0] = v0;
        ((float*)dout)[d * 2 + 1] = v1;
    }
}

extern "C" void kernel_launch(void* const* d_in, const int* in_sizes, int n_in,
                              void* d_out, int out_size, void* d_ws, size_t ws_size,
                              hipStream_t stream) {
    char* w = (char*)d_ws;
    unsigned* flag = (unsigned*)(w + (size_t)OFF_FLAG * 4);
    float* wb = (float*)(w + (size_t)OFF_W * 4);
    unsigned short* wt = (unsigned short*)(w + (size_t)OFF_WT * 4);
    float* bcat = (float*)(w + (size_t)OFF_BCAT * 4);
    __hip_bfloat16* xlb = (__hip_bfloat16*)(w + (size_t)OFF_XLB * 4);
    __hip_bfloat16* xrb = (__hip_bfloat16*)(w + (size_t)OFF_XRB * 4);
    int2* pairs = (int2*)(w + (size_t)OFF_PAIRS * 4);
    int* csr = (int*)(w + (size_t)OFF_CSR * 4);
    int* rowptr = (int*)(w + (size_t)OFF_ROWPTR * 4);
    int* S = (int*)(w + (size_t)OFF_S * 4);
    float* xl2 = (float*)(w + (size_t)OFF_XL2 * 4);
    float* xr2 = (float*)(w + (size_t)OFF_XR2 * 4);
    float* h = (float*)(w + (size_t)OFF_H * 4);
    const int* esrc = (const int*)d_in[1];
    const int* edst = (const int*)d_in[2];

    k_prep<<<(PREP_TOT + 255) / 256, 256, 0, stream>>>(
        (const unsigned short*)d_in[0],
        d_in[3], d_in[4], d_in[5], d_in[6], d_in[7], d_in[8],
        d_in[9], d_in[10], d_in[11], d_in[12], d_in[13], d_in[14],
        flag, wt, bcat, wb);

    // ---- CSR build ----
    k_pa_hist<<<NCHUNK, 256, 0, stream>>>(edst, S);
    k_pa_scan<<<1, 512, 0, stream>>>(S, rowptr);
    k_pa_scatter<<<NCHUNK, 256, 0, stream>>>(esrc, edst, S, pairs);
    k_bsort<<<NBUCK, 256, 0, stream>>>(S, pairs, rowptr, csr);

    // ---- layer-1 GEMM ----
    k_gemm1_mfma<<<NPAD / 64, 256, 0, stream>>>(d_in[0], flag, wt, bcat, xlb, xrb);

    // ---- layer-1 attention (R4 form) ----
    k_gat1<<<(N_NODES + 3) / 4, 256, 0, stream>>>(rowptr, csr, xlb, xrb,
                                                  wb + WO_ATT1, wb + WO_BIAS1, h);

    // ---- layer-2 projection ----
    k_gemm2<<<(N_NODES + 3) / 4, 256, 0, stream>>>(h, wb, xl2, xr2);

    // ---- layer-2 attention + output ----
    k_gat2<<<(N_NODES + 255) / 256, 256, 0, stream>>>(rowptr, csr, xl2, xr2,
                                                      wb, flag, d_out);
}

// Round 10
// 403.614 us; speedup vs baseline: 1.3730x; 1.1361x over previous
//
#include <hip/hip_runtime.h>
#include <hip/hip_bf16.h>

#define N_NODES 100000
#define NPAD 100032                         // 64-row-aligned node count
#define N_EDGES 1600000
#define ETOT (N_EDGES + N_NODES)
#define NFEAT 165
#define KP 192                              // K padded to 32-multiple
#define HID 128
#define NCLS 2
#define NEG 0.2f

// CSR radix-build parameters
#define NBUCK 391                           // ceil(N_NODES/256); bucket = dst >> 8
#define CHUNK 16384
#define NCHUNK 104                          // ceil(ETOT/CHUNK)

typedef short bf16x8 __attribute__((ext_vector_type(8)));
typedef float f32x4 __attribute__((ext_vector_type(4)));

// ---- workspace layout (units of 4 bytes) ----
#define OFF_FLAG 0
#define OFF_W 16
// weight sub-offsets (within wb = ws + OFF_W)
#define WO_ATT1 42496
#define WO_BIAS1 42624
#define WO_W2L 42752
#define WO_B2L 43008
#define WO_W2R 43010
#define WO_B2R 43266
#define WO_ATT2 43268
#define WO_BIAS2 43270

#define OFF_XB   43392
#define OFF_WT   (OFF_XB + NPAD * KP / 2)   // bf16 WT [256][192]
#define OFF_BCAT (OFF_WT + 256 * KP / 2)    // fp32 bias concat [256]
#define OFF_XLB  (OFF_BCAT + 256)           // bf16 xl rows [NPAD][128]
#define OFF_XRB  (OFF_XLB + NPAD * HID / 2) // bf16 xr rows
#define OFF_PAIRS (OFF_XRB + NPAD * HID / 2) // int2 pairs[ETOT]
#define OFF_CSR  (OFF_PAIRS + 2 * ETOT)     // csr_src[ETOT]
#define OFF_ROWPTR (OFF_CSR + ETOT)         // rowptr[N_NODES+1]
#define OFF_S    (OFF_ROWPTR + N_NODES + 8) // per-(bucket,chunk) offsets
#define OFF_XL2  (OFF_S + NBUCK * NCHUNK + 8)
#define OFF_XR2  (OFF_XL2 + N_NODES * NCLS)
#define OFF_H    (OFF_XR2 + N_NODES * NCLS) // fp32 h [N][128]
#define OFF_DL   (OFF_H + N_NODES * HID)    // fp32 dl[NPAD] = att1 . xl[n]
#define OFF_DR   (OFF_DL + NPAD)            // fp32 dr[NPAD] = att1 . xr[n]

__device__ __forceinline__ float bload16(unsigned short u) {
    return __uint_as_float(((unsigned)u) << 16);
}

// lrelu(v) = 0.6v + 0.4|v|
__device__ __forceinline__ float lrelu(float v) {
    return fmaf(0.4f, fabsf(v), 0.6f * v);
}

__device__ __forceinline__ void unpack8(uint4 q, float* f) {
    f[0] = __uint_as_float(q.x << 16); f[1] = __uint_as_float(q.x & 0xffff0000u);
    f[2] = __uint_as_float(q.y << 16); f[3] = __uint_as_float(q.y & 0xffff0000u);
    f[4] = __uint_as_float(q.z << 16); f[5] = __uint_as_float(q.z & 0xffff0000u);
    f[6] = __uint_as_float(q.w << 16); f[7] = __uint_as_float(q.w & 0xffff0000u);
}

__device__ __forceinline__ unsigned short f2b(float f) {
    __hip_bfloat16 b = __float2bfloat16(f);
    return *(unsigned short*)&b;
}

// wave-uniform dtype sniff: 64 halves of x; bf16 -> ~all plausible, fp32 -> ~58%
__device__ __forceinline__ unsigned detect_flag(const unsigned short* x16, int lane) {
    unsigned short hh = x16[lane];
    unsigned e = (hh >> 7) & 0xFF;
    bool pl = ((hh & 0x7FFF) == 0) || (e >= 100 && e <= 140);
    unsigned long long m = __ballot(pl);
    return (__popcll(m) >= 52) ? 1u : 0u;
}

// ---- fused: per-chunk bucket histogram (blocks 0..NCHUNK-1) + weight prep ----
#define PREP_WT 49152                       // 256*192
#define PREP_BC (PREP_WT + 256)
#define PREP_TOT (PREP_BC + 776)
#define PREP_BLKS ((PREP_TOT + 255) / 256)
__global__ void __launch_bounds__(256) k_prep_hist(
        const int* __restrict__ edst, int* __restrict__ bh,
        const unsigned short* __restrict__ x16,
        const void* W1l, const void* b1l, const void* W1r, const void* b1r,
        const void* att1, const void* bias1, const void* W2l, const void* b2l,
        const void* W2r, const void* b2r, const void* att2, const void* bias2,
        unsigned* __restrict__ flagp, unsigned short* __restrict__ wt,
        float* __restrict__ bcat, float* __restrict__ wb) {
    __shared__ int hist[NBUCK];
    if (blockIdx.x < NCHUNK) {
        for (int i = threadIdx.x; i < NBUCK; i += 256) hist[i] = 0;
        __syncthreads();
        int base = blockIdx.x * CHUNK;
        for (int i = threadIdx.x; i < CHUNK; i += 256) {
            int e = base + i;
            if (e >= ETOT) break;
            int d = (e < N_EDGES) ? edst[e] : (e - N_EDGES);
            atomicAdd(&hist[d >> 8], 1);
        }
        __syncthreads();
        for (int b = threadIdx.x; b < NBUCK; b += 256)
            bh[b * NCHUNK + blockIdx.x] = hist[b];
        return;
    }
    // ---- prep part ----
    int lane = threadIdx.x & 63;
    unsigned isbf = detect_flag(x16, lane);
    int i = (blockIdx.x - NCHUNK) * 256 + threadIdx.x;
    if (i == 0) *flagp = isbf;
    if (i >= PREP_TOT) return;
    if (i < PREP_WT) {
        int n = i / KP, k = i - n * KP;
        unsigned short v = 0;
        if (k < NFEAT) {
            const void* src = (n < HID) ? W1l : W1r;
            size_t off = (size_t)k * HID + (n & (HID - 1));
            v = isbf ? ((const unsigned short*)src)[off]
                     : f2b(((const float*)src)[off]);
        }
        wt[i] = v;
    } else if (i < PREP_BC) {
        int n = i - PREP_WT;
        const void* src = (n < HID) ? b1l : b1r;
        int off = n & (HID - 1);
        bcat[n] = isbf ? bload16(((const unsigned short*)src)[off])
                       : ((const float*)src)[off];
    } else {
        int j = i - PREP_BC;
        const void* src; int off; int dst;
        if      (j < 128) { src = att1;  off = j;       dst = WO_ATT1 + j; }
        else if (j < 256) { src = bias1; off = j - 128; dst = WO_BIAS1 + (j - 128); }
        else if (j < 512) { src = W2l;   off = j - 256; dst = WO_W2L + (j - 256); }
        else if (j < 514) { src = b2l;   off = j - 512; dst = WO_B2L + (j - 512); }
        else if (j < 770) { src = W2r;   off = j - 514; dst = WO_W2R + (j - 514); }
        else if (j < 772) { src = b2r;   off = j - 770; dst = WO_B2R + (j - 770); }
        else if (j < 774) { src = att2;  off = j - 772; dst = WO_ATT2 + (j - 772); }
        else              { src = bias2; off = j - 774; dst = WO_BIAS2 + (j - 774); }
        wb[dst] = isbf ? bload16(((const unsigned short*)src)[off])
                       : ((const float*)src)[off];
    }
}

// ---- exclusive scan of the NBUCK*NCHUNK counts (uint4-vectorized) ----
__global__ void __launch_bounds__(512) k_pa_scan(int* __restrict__ S,
                                                 int* __restrict__ rowptr) {
    __shared__ int lds[512];
    const int TOT4 = (NBUCK * NCHUNK) / 4;   // 10166, exact
    int t = threadIdx.x;
    int b4 = t * 20;
    uint4* S4 = (uint4*)S;
    int sum = 0;
    for (int k = 0; k < 20; k++) {
        int i = b4 + k;
        if (i < TOT4) {
            uint4 v = S4[i];
            sum += (int)(v.x + v.y + v.z + v.w);
        }
    }
    lds[t] = sum;
    __syncthreads();
    for (int off = 1; off < 512; off <<= 1) {
        int v = lds[t];
        if (t >= off) v += lds[t - off];
        __syncthreads();
        lds[t] = v;
        __syncthreads();
    }
    int carry = (t == 0) ? 0 : lds[t - 1];
    for (int k = 0; k < 20; k++) {
        int i = b4 + k;
        if (i < TOT4) {
            uint4 v = S4[i];
            uint4 o;
            o.x = carry; carry += v.x;
            o.y = carry; carry += v.y;
            o.z = carry; carry += v.z;
            o.w = carry; carry += v.w;
            S4[i] = o;
        }
    }
    if (t == 0) rowptr[N_NODES] = ETOT;
}

__global__ void __launch_bounds__(256) k_pa_scatter(const int* __restrict__ esrc,
                                                    const int* __restrict__ edst,
                                                    const int* __restrict__ S,
                                                    int2* __restrict__ pairs) {
    __shared__ int cur[NBUCK];
    for (int i = threadIdx.x; i < NBUCK; i += 256)
        cur[i] = S[i * NCHUNK + blockIdx.x];
    __syncthreads();
    int base = blockIdx.x * CHUNK;
    for (int i = threadIdx.x; i < CHUNK; i += 256) {
        int e = base + i;
        if (e >= ETOT) break;
        int s = (e < N_EDGES) ? esrc[e] : (e - N_EDGES);
        int d = (e < N_EDGES) ? edst[e] : (e - N_EDGES);
        int p = atomicAdd(&cur[d >> 8], 1);
        pairs[p] = make_int2(s, d);
    }
}

__global__ void __launch_bounds__(256) k_bsort(const int* __restrict__ S,
                                               const int2* __restrict__ pairs,
                                               int* __restrict__ rowptr,
                                               int* __restrict__ csr) {
    __shared__ int hist[256];
    __shared__ int cur[256];
    int b = blockIdx.x, t = threadIdx.x;
    int beg = S[b * NCHUNK];
    int end = (b == NBUCK - 1) ? ETOT : S[(b + 1) * NCHUNK];
    hist[t] = 0;
    __syncthreads();
    for (int j = beg + t; j < end; j += 256)
        atomicAdd(&hist[pairs[j].y & 255], 1);
    __syncthreads();
    for (int off = 1; off < 256; off <<= 1) {
        int v = hist[t];
        if (t >= off) v += hist[t - off];
        __syncthreads();
        hist[t] = v;
        __syncthreads();
    }
    int excl = (t == 0) ? 0 : hist[t - 1];
    int node = b * 256 + t;
    if (node < N_NODES) rowptr[node] = beg + excl;
    cur[t] = beg + excl;
    __syncthreads();
    for (int j = beg + t; j < end; j += 256) {
        int2 pr = pairs[j];
        int p = atomicAdd(&cur[pr.y & 255], 1);
        csr[p] = pr.x;
    }
}

// ================= layer-1 GEMM via bf16 MFMA (C^T trick) + att-dot epilogue =
// dl[n] = att1 . xl[n], dr[n] = att1 . xr[n] computed from in-register C values
// (waves 0,1 hold xl cols; waves 2,3 hold xr cols).
#define XS_STRIDE 200
__global__ void __launch_bounds__(256) k_gemm1_mfma(
        const void* __restrict__ x,
        const unsigned* __restrict__ flagp,
        const unsigned short* __restrict__ wt,
        const float* __restrict__ bcat,
        const float* __restrict__ attp,
        __hip_bfloat16* __restrict__ xlb,
        __hip_bfloat16* __restrict__ xrb,
        float* __restrict__ dl,
        float* __restrict__ dr) {
    __shared__ unsigned short xs[64 * XS_STRIDE];
    __shared__ float dpart[4][64];
    int tid = threadIdx.x;
    int wave = tid >> 6, lane = tid & 63;
    int quad = lane >> 4, li = lane & 15;
    int node0 = blockIdx.x * 64;
    unsigned isbf = *flagp;
    const float* xf = (const float*)x;
    const unsigned short* x16 = (const unsigned short*)x;

    // zero pad cols [165,192)
    for (int i = tid; i < 64 * 27; i += 256) {
        int r = i / 27, c = 165 + (i - r * 27);
        xs[r * XS_STRIDE + c] = 0;
    }
    if (node0 + 64 <= N_NODES) {
        if (isbf) {
            const uint4* src = (const uint4*)(x16 + (size_t)node0 * NFEAT);
            for (int i = tid; i < 1320; i += 256) {   // 1320*8 = 64*165 halves
                uint4 v = src[i];
                int f = i * 8;
                unsigned short hh[8] = {
                    (unsigned short)(v.x & 0xffff), (unsigned short)(v.x >> 16),
                    (unsigned short)(v.y & 0xffff), (unsigned short)(v.y >> 16),
                    (unsigned short)(v.z & 0xffff), (unsigned short)(v.z >> 16),
                    (unsigned short)(v.w & 0xffff), (unsigned short)(v.w >> 16)};
#pragma unroll
                for (int t = 0; t < 8; t++) {
                    int ff = f + t, r = ff / NFEAT, c = ff - r * NFEAT;
                    xs[r * XS_STRIDE + c] = hh[t];
                }
            }
        } else {
            const float4* src = (const float4*)(xf + (size_t)node0 * NFEAT);
            for (int i = tid; i < 2640; i += 256) {   // 2640*4 = 64*165 floats
                float4 v = src[i];
                int f = i * 4;
                unsigned short hh[4] = {f2b(v.x), f2b(v.y), f2b(v.z), f2b(v.w)};
#pragma unroll
                for (int t = 0; t < 4; t++) {
                    int ff = f + t, r = ff / NFEAT, c = ff - r * NFEAT;
                    xs[r * XS_STRIDE + c] = hh[t];
                }
            }
        }
    } else {
        for (int i = tid; i < 64 * NFEAT; i += 256) {
            int r = i / NFEAT, c = i - r * NFEAT;
            int grow = node0 + r;
            unsigned short v = 0;
            if (grow < N_NODES) {
                size_t g = (size_t)grow * NFEAT + c;
                v = isbf ? x16[g] : f2b(xf[g]);
            }
            xs[r * XS_STRIDE + c] = v;
        }
    }

    bf16x8 wfrag[4][6];
#pragma unroll
    for (int q = 0; q < 4; q++) {
        int n = wave * 64 + q * 16 + li;
#pragma unroll
        for (int kk = 0; kk < 6; kk++)
            wfrag[q][kk] = *(const bf16x8*)&wt[(size_t)n * KP + kk * 32 + quad * 8];
    }
    float4 bv[4], attq4[4];
    int colbase = (wave & 1) * 64;
#pragma unroll
    for (int q = 0; q < 4; q++) {
        bv[q] = *(const float4*)&bcat[wave * 64 + q * 16 + quad * 4];
        attq4[q] = *(const float4*)&attp[colbase + q * 16 + quad * 4];
    }
    __syncthreads();

    for (int mt = 0; mt < 4; mt++) {
        bf16x8 xfrag[6];
#pragma unroll
        for (int kk = 0; kk < 6; kk++)
            xfrag[kk] = *(const bf16x8*)&xs[(mt * 16 + li) * XS_STRIDE + kk * 32 + quad * 8];
        int node = node0 + mt * 16 + li;
        __hip_bfloat16* dst = (wave < 2) ? xlb : xrb;
        float dp = 0.f;
#pragma unroll
        for (int q = 0; q < 4; q++) {
            f32x4 a = {0.f, 0.f, 0.f, 0.f};
#pragma unroll
            for (int kk = 0; kk < 6; kk++)
                a = __builtin_amdgcn_mfma_f32_16x16x32_bf16(wfrag[q][kk], xfrag[kk], a, 0, 0, 0);
            float f0 = a[0] + bv[q].x, f1 = a[1] + bv[q].y;
            float f2 = a[2] + bv[q].z, f3 = a[3] + bv[q].w;
            dp = fmaf(f0, attq4[q].x, dp);
            dp = fmaf(f1, attq4[q].y, dp);
            dp = fmaf(f2, attq4[q].z, dp);
            dp = fmaf(f3, attq4[q].w, dp);
            unsigned short s0 = f2b(f0), s1 = f2b(f1);
            unsigned short s2 = f2b(f2), s3 = f2b(f3);
            uint2 val = { (unsigned)s0 | ((unsigned)s1 << 16),
                          (unsigned)s2 | ((unsigned)s3 << 16) };
            int col = colbase + q * 16 + quad * 4;
            *(uint2*)&dst[(size_t)node * HID + col] = val;
        }
        dp += __shfl_xor(dp, 16);
        dp += __shfl_xor(dp, 32);
        if (lane < 16) dpart[wave][mt * 16 + li] = dp;
    }
    __syncthreads();
    if (tid < 64)
        dl[node0 + tid] = dpart[0][tid] + dpart[1][tid];
    else if (tid < 128)
        dr[node0 + tid - 64] = dpart[2][tid - 64] + dpart[3][tid - 64];
}

// ================= fused layer-1 attention (separable-score form) ============
// score = 0.6*(dl[s]+dr[d]) + sum (0.4*att)[t]*|xl[s][t]+xr[d][t]|
// Loop keeps the R4 pipelined-gather structure; only the score math changed.
__global__ void __launch_bounds__(256) k_gat1(const int* __restrict__ rowptr,
                                              const int* __restrict__ csr,
                                              const __hip_bfloat16* __restrict__ xlb,
                                              const __hip_bfloat16* __restrict__ xrb,
                                              const float* __restrict__ att,
                                              const float* __restrict__ bias,
                                              const float* __restrict__ dotsl,
                                              const float* __restrict__ dotsr,
                                              float* __restrict__ h) {
    int wave = threadIdx.x >> 6, lane = threadIdx.x & 63;
    int d = blockIdx.x * 4 + wave;
    if (d >= N_NODES) return;
    int sub = lane >> 4, li = lane & 15;

    uint4 qr = ((const uint4*)(xrb + (size_t)d * HID))[li];
    float xrv[8]; unpack8(qr, xrv);
    float atv[8];
    {
        float4 t0 = ((const float4*)att)[li * 2];
        float4 t1 = ((const float4*)att)[li * 2 + 1];
        atv[0] = 0.4f * t0.x; atv[1] = 0.4f * t0.y;
        atv[2] = 0.4f * t0.z; atv[3] = 0.4f * t0.w;
        atv[4] = 0.4f * t1.x; atv[5] = 0.4f * t1.y;
        atv[6] = 0.4f * t1.z; atv[7] = 0.4f * t1.w;
    }
    float drd = dotsr[d];
    int beg = rowptr[d], end = rowptr[d + 1];
    int iters = (end - beg + 3) >> 2;
    float l = 0.f, o[8];
#pragma unroll
    for (int t = 0; t < 8; t++) o[t] = 0.f;

    int j = beg + sub;
    bool valid = j < end;
    int s = valid ? csr[j] : 0;
    uint4 q = *(const uint4*)(xlb + (size_t)s * HID + li * 8);
    float dlc = dotsl[s];

    for (int it = 0; it < iters; it++) {
        float c[8]; unpack8(q, c);
        bool v = valid;
        float dle = dlc;
        j += 4;
        valid = j < end;
        int sn = valid ? csr[j] : 0;
        q = *(const uint4*)(xlb + (size_t)sn * HID + li * 8);
        dlc = dotsl[sn];

        float pa = 0.f;
#pragma unroll
        for (int t = 0; t < 8; t++) {
            float vv = c[t] + xrv[t];
            pa = fmaf(atv[t], fabsf(vv), pa);
        }
        pa += __shfl_xor(pa, 1);
        pa += __shfl_xor(pa, 2);
        pa += __shfl_xor(pa, 4);
        pa += __shfl_xor(pa, 8);
        float p = fmaf(0.6f, dle + drd, pa);
        float a = v ? __expf(p) : 0.f;
        l += a;
#pragma unroll
        for (int t = 0; t < 8; t++) o[t] = fmaf(a, c[t], o[t]);
    }
    // merge the 4 subgroups
    l += __shfl_xor(l, 16);
    l += __shfl_xor(l, 32);
#pragma unroll
    for (int t = 0; t < 8; t++) {
        o[t] += __shfl_xor(o[t], 16);
        o[t] += __shfl_xor(o[t], 32);
    }
    if (sub == 0) {
        float inv = 1.f / l;  // self-loop guarantees l > 0
        float4 bv0 = ((const float4*)bias)[li * 2];
        float4 bv1 = ((const float4*)bias)[li * 2 + 1];
        float4 r0, r1;
        r0.x = fmaf(o[0], inv, bv0.x); r0.y = fmaf(o[1], inv, bv0.y);
        r0.z = fmaf(o[2], inv, bv0.z); r0.w = fmaf(o[3], inv, bv0.w);
        r1.x = fmaf(o[4], inv, bv1.x); r1.y = fmaf(o[5], inv, bv1.y);
        r1.z = fmaf(o[6], inv, bv1.z); r1.w = fmaf(o[7], inv, bv1.w);
        r0.x = fmaxf(r0.x, 0.f); r0.y = fmaxf(r0.y, 0.f);
        r0.z = fmaxf(r0.z, 0.f); r0.w = fmaxf(r0.w, 0.f);
        r1.x = fmaxf(r1.x, 0.f); r1.y = fmaxf(r1.y, 0.f);
        r1.z = fmaxf(r1.z, 0.f); r1.w = fmaxf(r1.w, 0.f);
        float4* hp = (float4*)(h + (size_t)d * HID + li * 8);
        hp[0] = r0;
        hp[1] = r1;
    }
}

// ================= layer-2 GEMMs: wave per node, shuffle K-reduce ============
__global__ void __launch_bounds__(256) k_gemm2(const float* __restrict__ h,
                                               const float* __restrict__ wb,
                                               float* __restrict__ xl2, float* __restrict__ xr2) {
    const float* W2l = wb + WO_W2L;
    const float* b2l = wb + WO_B2L;
    const float* W2r = wb + WO_W2R;
    const float* b2r = wb + WO_B2R;
    int wave = threadIdx.x >> 6, lane = threadIdx.x & 63;
    int node = blockIdx.x * 4 + wave;
    if (node >= N_NODES) return;
    const float* hr = h + (size_t)node * HID;
    float h0 = hr[lane], h1 = hr[lane + 64];
    float al0 = h0 * W2l[lane * 2 + 0] + h1 * W2l[(lane + 64) * 2 + 0];
    float al1 = h0 * W2l[lane * 2 + 1] + h1 * W2l[(lane + 64) * 2 + 1];
    float ar0 = h0 * W2r[lane * 2 + 0] + h1 * W2r[(lane + 64) * 2 + 0];
    float ar1 = h0 * W2r[lane * 2 + 1] + h1 * W2r[(lane + 64) * 2 + 1];
#pragma unroll
    for (int off = 32; off > 0; off >>= 1) {
        al0 += __shfl_down(al0, off);
        al1 += __shfl_down(al1, off);
        ar0 += __shfl_down(ar0, off);
        ar1 += __shfl_down(ar1, off);
    }
    if (lane == 0) {
        xl2[node * 2 + 0] = al0 + b2l[0];
        xl2[node * 2 + 1] = al1 + b2l[1];
        xr2[node * 2 + 0] = ar0 + b2r[0];
        xr2[node * 2 + 1] = ar1 + b2r[1];
    }
}

// ================= fused layer-2 attention: thread per dst node ==============
__global__ void __launch_bounds__(256) k_gat2(const int* __restrict__ rowptr,
                                              const int* __restrict__ csr,
                                              const float* __restrict__ xl2,
                                              const float* __restrict__ xr2,
                                              const float* __restrict__ wb,
                                              const unsigned* __restrict__ flag,
                                              void* __restrict__ dout) {
    int d = blockIdx.x * 256 + threadIdx.x;
    if (d >= N_NODES) return;
    float xr0 = xr2[d * 2 + 0], xr1 = xr2[d * 2 + 1];
    float at0 = wb[WO_ATT2], at1 = wb[WO_ATT2 + 1];
    int beg = rowptr[d], end = rowptr[d + 1];
    float l = 0.f, o0 = 0.f, o1 = 0.f;
    for (int j = beg; j < end; j++) {
        int s = csr[j];
        float b0 = xl2[s * 2 + 0], b1 = xl2[s * 2 + 1];
        float p = at0 * lrelu(b0 + xr0) + at1 * lrelu(b1 + xr1);
        float a = __expf(p);
        l += a;
        o0 = fmaf(a, b0, o0);
        o1 = fmaf(a, b1, o1);
    }
    float inv = 1.f / l;
    float v0 = fmaf(o0, inv, wb[WO_BIAS2 + 0]);
    float v1 = fmaf(o1, inv, wb[WO_BIAS2 + 1]);
    if (*flag) {
        ((__hip_bfloat16*)dout)[d * 2 + 0] = __float2bfloat16(v0);
        ((__hip_bfloat16*)dout)[d * 2 + 1] = __float2bfloat16(v1);
    } else {
        ((float*)dout)[d * 2 + 0] = v0;
        ((float*)dout)[d * 2 + 1] = v1;
    }
}

extern "C" void kernel_launch(void* const* d_in, const int* in_sizes, int n_in,
                              void* d_out, int out_size, void* d_ws, size_t ws_size,
                              hipStream_t stream) {
    char* w = (char*)d_ws;
    unsigned* flag = (unsigned*)(w + (size_t)OFF_FLAG * 4);
    float* wb = (float*)(w + (size_t)OFF_W * 4);
    unsigned short* wt = (unsigned short*)(w + (size_t)OFF_WT * 4);
    float* bcat = (float*)(w + (size_t)OFF_BCAT * 4);
    __hip_bfloat16* xlb = (__hip_bfloat16*)(w + (size_t)OFF_XLB * 4);
    __hip_bfloat16* xrb = (__hip_bfloat16*)(w + (size_t)OFF_XRB * 4);
    int2* pairs = (int2*)(w + (size_t)OFF_PAIRS * 4);
    int* csr = (int*)(w + (size_t)OFF_CSR * 4);
    int* rowptr = (int*)(w + (size_t)OFF_ROWPTR * 4);
    int* S = (int*)(w + (size_t)OFF_S * 4);
    float* xl2 = (float*)(w + (size_t)OFF_XL2 * 4);
    float* xr2 = (float*)(w + (size_t)OFF_XR2 * 4);
    float* h = (float*)(w + (size_t)OFF_H * 4);
    float* dl = (float*)(w + (size_t)OFF_DL * 4);
    float* dr = (float*)(w + (size_t)OFF_DR * 4);
    const int* esrc = (const int*)d_in[1];
    const int* edst = (const int*)d_in[2];

    // ---- fused prep + per-chunk histogram ----
    k_prep_hist<<<NCHUNK + PREP_BLKS, 256, 0, stream>>>(
        edst, S, (const unsigned short*)d_in[0],
        d_in[3], d_in[4], d_in[5], d_in[6], d_in[7], d_in[8],
        d_in[9], d_in[10], d_in[11], d_in[12], d_in[13], d_in[14],
        flag, wt, bcat, wb);

    // ---- CSR build ----
    k_pa_scan<<<1, 512, 0, stream>>>(S, rowptr);
    k_pa_scatter<<<NCHUNK, 256, 0, stream>>>(esrc, edst, S, pairs);
    k_bsort<<<NBUCK, 256, 0, stream>>>(S, pairs, rowptr, csr);

    // ---- layer-1 GEMM + att-dot epilogue ----
    k_gemm1_mfma<<<NPAD / 64, 256, 0, stream>>>(d_in[0], flag, wt, bcat,
                                                wb + WO_ATT1, xlb, xrb, dl, dr);

    // ---- layer-1 attention (separable score) ----
    k_gat1<<<(N_NODES + 3) / 4, 256, 0, stream>>>(rowptr, csr, xlb, xrb,
                                                  wb + WO_ATT1, wb + WO_BIAS1,
                                                  dl, dr, h);

    // ---- layer-2 projection ----
    k_gemm2<<<(N_NODES + 3) / 4, 256, 0, stream>>>(h, wb, xl2, xr2);

    // ---- layer-2 attention + output ----
    k_gat2<<<(N_NODES + 255) / 256, 256, 0, stream>>>(rowptr, csr, xl2, xr2,
                                                      wb, flag, d_out);
}

// Round 11
// 396.471 us; speedup vs baseline: 1.3977x; 1.0180x over previous
//
#include <hip/hip_runtime.h>
#include <hip/hip_bf16.h>

#define N_NODES 100000
#define NPAD 100032                         // 64-row-aligned node count
#define N_EDGES 1600000
#define ETOT (N_EDGES + N_NODES)
#define NFEAT 165
#define KP 192                              // K padded to 32-multiple
#define HID 128
#define NCLS 2
#define NEG 0.2f

// CSR radix-build parameters
#define NBUCK 391                           // ceil(N_NODES/256); bucket = dst >> 8
#define CHUNK 16384
#define NCHUNK 104                          // ceil(ETOT/CHUNK)
#define GS_BLOCKS 2048                      // gat1 grid: 8192 waves = device capacity

typedef short bf16x8 __attribute__((ext_vector_type(8)));
typedef float f32x4 __attribute__((ext_vector_type(4)));

// ---- workspace layout (units of 4 bytes) ----
#define OFF_FLAG 0
#define OFF_W 16
// weight sub-offsets (within wb = ws + OFF_W)
#define WO_ATT1 42496
#define WO_BIAS1 42624
#define WO_W2L 42752
#define WO_B2L 43008
#define WO_W2R 43010
#define WO_B2R 43266
#define WO_ATT2 43268
#define WO_BIAS2 43270

#define OFF_XB   43392
#define OFF_W2A  OFF_XB                     // 16-B-aligned W2l[256]|W2r[256] copy
#define OFF_WT   (OFF_XB + NPAD * KP / 2)   // bf16 WT [256][192]
#define OFF_BCAT (OFF_WT + 256 * KP / 2)    // fp32 bias concat [256]
#define OFF_XLB  (OFF_BCAT + 256)           // bf16 xl rows [NPAD][128]
#define OFF_XRB  (OFF_XLB + NPAD * HID / 2) // bf16 xr rows
#define OFF_PAIRS (OFF_XRB + NPAD * HID / 2) // packed uint pairs[ETOT]
#define OFF_CSR  (OFF_PAIRS + 2 * ETOT)     // csr_src[ETOT]
#define OFF_ROWPTR (OFF_CSR + ETOT)         // rowptr[N_NODES+1]
#define OFF_S    (OFF_ROWPTR + N_NODES + 8) // per-(bucket,chunk) offsets
#define OFF_XL2  (OFF_S + NBUCK * NCHUNK + 8)
#define OFF_XR2  (OFF_XL2 + N_NODES * NCLS)
#define OFF_H    (OFF_XR2 + N_NODES * NCLS) // bf16 h [N][128]
#define OFF_DL   (OFF_H + N_NODES * HID)    // fp32 dl[NPAD] = att1 . xl[n]
#define OFF_DR   (OFF_DL + NPAD)            // fp32 dr[NPAD] = att1 . xr[n]

__device__ __forceinline__ float bload16(unsigned short u) {
    return __uint_as_float(((unsigned)u) << 16);
}

// lrelu(v) = 0.6v + 0.4|v|
__device__ __forceinline__ float lrelu(float v) {
    return fmaf(0.4f, fabsf(v), 0.6f * v);
}

__device__ __forceinline__ void unpack8(uint4 q, float* f) {
    f[0] = __uint_as_float(q.x << 16); f[1] = __uint_as_float(q.x & 0xffff0000u);
    f[2] = __uint_as_float(q.y << 16); f[3] = __uint_as_float(q.y & 0xffff0000u);
    f[4] = __uint_as_float(q.z << 16); f[5] = __uint_as_float(q.z & 0xffff0000u);
    f[6] = __uint_as_float(q.w << 16); f[7] = __uint_as_float(q.w & 0xffff0000u);
}

__device__ __forceinline__ unsigned short f2b(float f) {
    __hip_bfloat16 b = __float2bfloat16(f);
    return *(unsigned short*)&b;
}

__device__ __forceinline__ unsigned pack2(float a, float b) {
    return (unsigned)f2b(a) | ((unsigned)f2b(b) << 16);
}

// wave-uniform dtype sniff: 64 halves of x; bf16 -> ~all plausible, fp32 -> ~58%
__device__ __forceinline__ unsigned detect_flag(const unsigned short* x16, int lane) {
    unsigned short hh = x16[lane];
    unsigned e = (hh >> 7) & 0xFF;
    bool pl = ((hh & 0x7FFF) == 0) || (e >= 100 && e <= 140);
    unsigned long long m = __ballot(pl);
    return (__popcll(m) >= 52) ? 1u : 0u;
}

// ---- fused: per-chunk bucket histogram (blocks 0..NCHUNK-1) + weight prep ----
#define PREP_WT 49152                       // 256*192
#define PREP_BC (PREP_WT + 256)
#define PREP_TOT (PREP_BC + 776)
#define PREP_BLKS ((PREP_TOT + 255) / 256)
__global__ void __launch_bounds__(256) k_prep_hist(
        const int* __restrict__ edst, int* __restrict__ bh,
        const unsigned short* __restrict__ x16,
        const void* W1l, const void* b1l, const void* W1r, const void* b1r,
        const void* att1, const void* bias1, const void* W2l, const void* b2l,
        const void* W2r, const void* b2r, const void* att2, const void* bias2,
        unsigned* __restrict__ flagp, unsigned short* __restrict__ wt,
        float* __restrict__ bcat, float* __restrict__ wb,
        float* __restrict__ w2a) {
    __shared__ int hist[NBUCK];
    if (blockIdx.x < NCHUNK) {
        for (int i = threadIdx.x; i < NBUCK; i += 256) hist[i] = 0;
        __syncthreads();
        int base = blockIdx.x * CHUNK;
        for (int i = threadIdx.x; i < CHUNK; i += 256) {
            int e = base + i;
            if (e >= ETOT) break;
            int d = (e < N_EDGES) ? edst[e] : (e - N_EDGES);
            atomicAdd(&hist[d >> 8], 1);
        }
        __syncthreads();
        for (int b = threadIdx.x; b < NBUCK; b += 256)
            bh[b * NCHUNK + blockIdx.x] = hist[b];
        return;
    }
    // ---- prep part ----
    int lane = threadIdx.x & 63;
    unsigned isbf = detect_flag(x16, lane);
    int i = (blockIdx.x - NCHUNK) * 256 + threadIdx.x;
    if (i == 0) *flagp = isbf;
    if (i >= PREP_TOT) return;
    if (i < PREP_WT) {
        int n = i / KP, k = i - n * KP;
        unsigned short v = 0;
        if (k < NFEAT) {
            const void* src = (n < HID) ? W1l : W1r;
            size_t off = (size_t)k * HID + (n & (HID - 1));
            v = isbf ? ((const unsigned short*)src)[off]
                     : f2b(((const float*)src)[off]);
        }
        wt[i] = v;
    } else if (i < PREP_BC) {
        int n = i - PREP_WT;
        const void* src = (n < HID) ? b1l : b1r;
        int off = n & (HID - 1);
        bcat[n] = isbf ? bload16(((const unsigned short*)src)[off])
                       : ((const float*)src)[off];
    } else {
        int j = i - PREP_BC;
        const void* src; int off; int dst;
        if      (j < 128) { src = att1;  off = j;       dst = WO_ATT1 + j; }
        else if (j < 256) { src = bias1; off = j - 128; dst = WO_BIAS1 + (j - 128); }
        else if (j < 512) { src = W2l;   off = j - 256; dst = WO_W2L + (j - 256); }
        else if (j < 514) { src = b2l;   off = j - 512; dst = WO_B2L + (j - 512); }
        else if (j < 770) { src = W2r;   off = j - 514; dst = WO_W2R + (j - 514); }
        else if (j < 772) { src = b2r;   off = j - 770; dst = WO_B2R + (j - 770); }
        else if (j < 774) { src = att2;  off = j - 772; dst = WO_ATT2 + (j - 772); }
        else              { src = bias2; off = j - 774; dst = WO_BIAS2 + (j - 774); }
        float val = isbf ? bload16(((const unsigned short*)src)[off])
                         : ((const float*)src)[off];
        wb[dst] = val;
        // 16-B-aligned copy of W2l|W2r for gemm2's float4 loads
        if (j >= 256 && j < 512) w2a[j - 256] = val;
        else if (j >= 514 && j < 770) w2a[256 + (j - 514)] = val;
    }
}

// ---- exclusive scan of the NBUCK*NCHUNK counts (uint4-vectorized) ----
__global__ void __launch_bounds__(512) k_pa_scan(int* __restrict__ S,
                                                 int* __restrict__ rowptr) {
    __shared__ int lds[512];
    const int TOT4 = (NBUCK * NCHUNK) / 4;   // 10166, exact
    int t = threadIdx.x;
    int b4 = t * 20;
    uint4* S4 = (uint4*)S;
    int sum = 0;
    for (int k = 0; k < 20; k++) {
        int i = b4 + k;
        if (i < TOT4) {
            uint4 v = S4[i];
            sum += (int)(v.x + v.y + v.z + v.w);
        }
    }
    lds[t] = sum;
    __syncthreads();
    for (int off = 1; off < 512; off <<= 1) {
        int v = lds[t];
        if (t >= off) v += lds[t - off];
        __syncthreads();
        lds[t] = v;
        __syncthreads();
    }
    int carry = (t == 0) ? 0 : lds[t - 1];
    for (int k = 0; k < 20; k++) {
        int i = b4 + k;
        if (i < TOT4) {
            uint4 v = S4[i];
            uint4 o;
            o.x = carry; carry += v.x;
            o.y = carry; carry += v.y;
            o.z = carry; carry += v.z;
            o.w = carry; carry += v.w;
            S4[i] = o;
        }
    }
    if (t == 0) rowptr[N_NODES] = ETOT;
}

// pairs entry: src (bits 0..16) | (dst & 255) << 24
__global__ void __launch_bounds__(256) k_pa_scatter(const int* __restrict__ esrc,
                                                    const int* __restrict__ edst,
                                                    const int* __restrict__ S,
                                                    unsigned* __restrict__ pairs) {
    __shared__ int cur[NBUCK];
    for (int i = threadIdx.x; i < NBUCK; i += 256)
        cur[i] = S[i * NCHUNK + blockIdx.x];
    __syncthreads();
    int base = blockIdx.x * CHUNK;
    for (int i = threadIdx.x; i < CHUNK; i += 256) {
        int e = base + i;
        if (e >= ETOT) break;
        int s = (e < N_EDGES) ? esrc[e] : (e - N_EDGES);
        int d = (e < N_EDGES) ? edst[e] : (e - N_EDGES);
        int p = atomicAdd(&cur[d >> 8], 1);
        pairs[p] = (unsigned)s | ((unsigned)(d & 255) << 24);
    }
}

__global__ void __launch_bounds__(256) k_bsort(const int* __restrict__ S,
                                               const unsigned* __restrict__ pairs,
                                               int* __restrict__ rowptr,
                                               int* __restrict__ csr) {
    __shared__ int hist[256];
    __shared__ int cur[256];
    int b = blockIdx.x, t = threadIdx.x;
    int beg = S[b * NCHUNK];
    int end = (b == NBUCK - 1) ? ETOT : S[(b + 1) * NCHUNK];
    hist[t] = 0;
    __syncthreads();
    for (int j = beg + t; j < end; j += 256)
        atomicAdd(&hist[pairs[j] >> 24], 1);
    __syncthreads();
    for (int off = 1; off < 256; off <<= 1) {
        int v = hist[t];
        if (t >= off) v += hist[t - off];
        __syncthreads();
        hist[t] = v;
        __syncthreads();
    }
    int excl = (t == 0) ? 0 : hist[t - 1];
    int node = b * 256 + t;
    if (node < N_NODES) rowptr[node] = beg + excl;
    cur[t] = beg + excl;
    __syncthreads();
    for (int j = beg + t; j < end; j += 256) {
        unsigned pr = pairs[j];
        int p = atomicAdd(&cur[pr >> 24], 1);
        csr[p] = (int)(pr & 0xFFFFFFu);
    }
}

// ================= layer-1 GEMM via bf16 MFMA (C^T trick) + att-dot epilogue =
#define XS_STRIDE 200
__global__ void __launch_bounds__(256) k_gemm1_mfma(
        const void* __restrict__ x,
        const unsigned* __restrict__ flagp,
        const unsigned short* __restrict__ wt,
        const float* __restrict__ bcat,
        const float* __restrict__ attp,
        __hip_bfloat16* __restrict__ xlb,
        __hip_bfloat16* __restrict__ xrb,
        float* __restrict__ dl,
        float* __restrict__ dr) {
    __shared__ unsigned short xs[64 * XS_STRIDE];
    __shared__ float dpart[4][64];
    int tid = threadIdx.x;
    int wave = tid >> 6, lane = tid & 63;
    int quad = lane >> 4, li = lane & 15;
    int node0 = blockIdx.x * 64;
    unsigned isbf = *flagp;
    const float* xf = (const float*)x;
    const unsigned short* x16 = (const unsigned short*)x;

    // zero pad cols [165,192)
    for (int i = tid; i < 64 * 27; i += 256) {
        int r = i / 27, c = 165 + (i - r * 27);
        xs[r * XS_STRIDE + c] = 0;
    }
    if (node0 + 64 <= N_NODES) {
        if (isbf) {
            const uint4* src = (const uint4*)(x16 + (size_t)node0 * NFEAT);
            for (int i = tid; i < 1320; i += 256) {   // 1320*8 = 64*165 halves
                uint4 v = src[i];
                int f = i * 8;
                unsigned short hh[8] = {
                    (unsigned short)(v.x & 0xffff), (unsigned short)(v.x >> 16),
                    (unsigned short)(v.y & 0xffff), (unsigned short)(v.y >> 16),
                    (unsigned short)(v.z & 0xffff), (unsigned short)(v.z >> 16),
                    (unsigned short)(v.w & 0xffff), (unsigned short)(v.w >> 16)};
#pragma unroll
                for (int t = 0; t < 8; t++) {
                    int ff = f + t, r = ff / NFEAT, c = ff - r * NFEAT;
                    xs[r * XS_STRIDE + c] = hh[t];
                }
            }
        } else {
            const float4* src = (const float4*)(xf + (size_t)node0 * NFEAT);
            for (int i = tid; i < 2640; i += 256) {   // 2640*4 = 64*165 floats
                float4 v = src[i];
                int f = i * 4;
                unsigned short hh[4] = {f2b(v.x), f2b(v.y), f2b(v.z), f2b(v.w)};
#pragma unroll
                for (int t = 0; t < 4; t++) {
                    int ff = f + t, r = ff / NFEAT, c = ff - r * NFEAT;
                    xs[r * XS_STRIDE + c] = hh[t];
                }
            }
        }
    } else {
        for (int i = tid; i < 64 * NFEAT; i += 256) {
            int r = i / NFEAT, c = i - r * NFEAT;
            int grow = node0 + r;
            unsigned short v = 0;
            if (grow < N_NODES) {
                size_t g = (size_t)grow * NFEAT + c;
                v = isbf ? x16[g] : f2b(xf[g]);
            }
            xs[r * XS_STRIDE + c] = v;
        }
    }

    bf16x8 wfrag[4][6];
#pragma unroll
    for (int q = 0; q < 4; q++) {
        int n = wave * 64 + q * 16 + li;
#pragma unroll
        for (int kk = 0; kk < 6; kk++)
            wfrag[q][kk] = *(const bf16x8*)&wt[(size_t)n * KP + kk * 32 + quad * 8];
    }
    float4 bv[4], attq4[4];
    int colbase = (wave & 1) * 64;
#pragma unroll
    for (int q = 0; q < 4; q++) {
        bv[q] = *(const float4*)&bcat[wave * 64 + q * 16 + quad * 4];
        attq4[q] = *(const float4*)&attp[colbase + q * 16 + quad * 4];
    }
    __syncthreads();

    for (int mt = 0; mt < 4; mt++) {
        bf16x8 xfrag[6];
#pragma unroll
        for (int kk = 0; kk < 6; kk++)
            xfrag[kk] = *(const bf16x8*)&xs[(mt * 16 + li) * XS_STRIDE + kk * 32 + quad * 8];
        int node = node0 + mt * 16 + li;
        __hip_bfloat16* dst = (wave < 2) ? xlb : xrb;
        float dp = 0.f;
#pragma unroll
        for (int q = 0; q < 4; q++) {
            f32x4 a = {0.f, 0.f, 0.f, 0.f};
#pragma unroll
            for (int kk = 0; kk < 6; kk++)
                a = __builtin_amdgcn_mfma_f32_16x16x32_bf16(wfrag[q][kk], xfrag[kk], a, 0, 0, 0);
            float f0 = a[0] + bv[q].x, f1 = a[1] + bv[q].y;
            float f2 = a[2] + bv[q].z, f3 = a[3] + bv[q].w;
            dp = fmaf(f0, attq4[q].x, dp);
            dp = fmaf(f1, attq4[q].y, dp);
            dp = fmaf(f2, attq4[q].z, dp);
            dp = fmaf(f3, attq4[q].w, dp);
            uint2 val = { pack2(f0, f1), pack2(f2, f3) };
            int col = colbase + q * 16 + quad * 4;
            *(uint2*)&dst[(size_t)node * HID + col] = val;
        }
        dp += __shfl_xor(dp, 16);
        dp += __shfl_xor(dp, 32);
        if (lane < 16) dpart[wave][mt * 16 + li] = dp;
    }
    __syncthreads();
    if (tid < 64)
        dl[node0 + tid] = dpart[0][tid] + dpart[1][tid];
    else if (tid < 128)
        dr[node0 + tid - 64] = dpart[2][tid - 64] + dpart[3][tid - 64];
}

// ================= fused layer-1 attention (separable score, grid-stride) ====
// score = 0.6*(dl[s]+dr[d]) + sum (0.4*att)[t]*|xl[s][t]+xr[d][t]|
// Inner loop is the measured-fast R9 form, untouched. Grid-stride over nodes
// (8192 waves = device capacity) to average out degree imbalance.
__global__ void __launch_bounds__(256) k_gat1(const int* __restrict__ rowptr,
                                              const int* __restrict__ csr,
                                              const __hip_bfloat16* __restrict__ xlb,
                                              const __hip_bfloat16* __restrict__ xrb,
                                              const float* __restrict__ att,
                                              const float* __restrict__ bias,
                                              const float* __restrict__ dotsl,
                                              const float* __restrict__ dotsr,
                                              unsigned short* __restrict__ h16) {
    int wave = threadIdx.x >> 6, lane = threadIdx.x & 63;
    int sub = lane >> 4, li = lane & 15;
    float atv[8];
    {
        float4 t0 = ((const float4*)att)[li * 2];
        float4 t1 = ((const float4*)att)[li * 2 + 1];
        atv[0] = 0.4f * t0.x; atv[1] = 0.4f * t0.y;
        atv[2] = 0.4f * t0.z; atv[3] = 0.4f * t0.w;
        atv[4] = 0.4f * t1.x; atv[5] = 0.4f * t1.y;
        atv[6] = 0.4f * t1.z; atv[7] = 0.4f * t1.w;
    }

    for (int d = blockIdx.x * 4 + wave; d < N_NODES; d += GS_BLOCKS * 4) {
        uint4 qr = ((const uint4*)(xrb + (size_t)d * HID))[li];
        float xrv[8]; unpack8(qr, xrv);
        float drd = dotsr[d];
        int beg = rowptr[d], end = rowptr[d + 1];
        int iters = (end - beg + 3) >> 2;
        float l = 0.f, o[8];
#pragma unroll
        for (int t = 0; t < 8; t++) o[t] = 0.f;

        int j = beg + sub;
        bool valid = j < end;
        int s = valid ? csr[j] : 0;
        uint4 q = *(const uint4*)(xlb + (size_t)s * HID + li * 8);
        float dlc = dotsl[s];

        for (int it = 0; it < iters; it++) {
            float c[8]; unpack8(q, c);
            bool v = valid;
            float dle = dlc;
            j += 4;
            valid = j < end;
            int sn = valid ? csr[j] : 0;
            q = *(const uint4*)(xlb + (size_t)sn * HID + li * 8);
            dlc = dotsl[sn];

            float pa = 0.f;
#pragma unroll
            for (int t = 0; t < 8; t++) {
                float vv = c[t] + xrv[t];
                pa = fmaf(atv[t], fabsf(vv), pa);
            }
            pa += __shfl_xor(pa, 1);
            pa += __shfl_xor(pa, 2);
            pa += __shfl_xor(pa, 4);
            pa += __shfl_xor(pa, 8);
            float p = fmaf(0.6f, dle + drd, pa);
            float a = v ? __expf(p) : 0.f;
            l += a;
#pragma unroll
            for (int t = 0; t < 8; t++) o[t] = fmaf(a, c[t], o[t]);
        }
        // merge the 4 subgroups
        l += __shfl_xor(l, 16);
        l += __shfl_xor(l, 32);
#pragma unroll
        for (int t = 0; t < 8; t++) {
            o[t] += __shfl_xor(o[t], 16);
            o[t] += __shfl_xor(o[t], 32);
        }
        if (sub == 0) {
            float inv = 1.f / l;  // self-loop guarantees l > 0
            float4 bv0 = ((const float4*)bias)[li * 2];
            float4 bv1 = ((const float4*)bias)[li * 2 + 1];
            float r0 = fmaxf(fmaf(o[0], inv, bv0.x), 0.f);
            float r1 = fmaxf(fmaf(o[1], inv, bv0.y), 0.f);
            float r2 = fmaxf(fmaf(o[2], inv, bv0.z), 0.f);
            float r3 = fmaxf(fmaf(o[3], inv, bv0.w), 0.f);
            float r4 = fmaxf(fmaf(o[4], inv, bv1.x), 0.f);
            float r5 = fmaxf(fmaf(o[5], inv, bv1.y), 0.f);
            float r6 = fmaxf(fmaf(o[6], inv, bv1.z), 0.f);
            float r7 = fmaxf(fmaf(o[7], inv, bv1.w), 0.f);
            uint4 val = { pack2(r0, r1), pack2(r2, r3),
                          pack2(r4, r5), pack2(r6, r7) };
            *(uint4*)&h16[(size_t)d * HID + li * 8] = val;
        }
    }
}

// ================= layer-2 GEMMs: wave per node (bf16 h, float4 weights) =====
__global__ void __launch_bounds__(256) k_gemm2(const unsigned short* __restrict__ h16,
                                               const float* __restrict__ wb,
                                               const float* __restrict__ w2a,
                                               float* __restrict__ xl2, float* __restrict__ xr2) {
    int wave = threadIdx.x >> 6, lane = threadIdx.x & 63;
    int node = blockIdx.x * 4 + wave;
    if (node >= N_NODES) return;
    unsigned hw = ((const unsigned*)(h16 + (size_t)node * HID))[lane];
    float h0 = __uint_as_float(hw << 16);            // col 2*lane
    float h1 = __uint_as_float(hw & 0xffff0000u);    // col 2*lane+1
    float4 wl = ((const float4*)w2a)[lane];          // W2l rows 2*lane, 2*lane+1
    float4 wr = ((const float4*)(w2a + 256))[lane];  // W2r rows 2*lane, 2*lane+1
    float al0 = h0 * wl.x + h1 * wl.z;
    float al1 = h0 * wl.y + h1 * wl.w;
    float ar0 = h0 * wr.x + h1 * wr.z;
    float ar1 = h0 * wr.y + h1 * wr.w;
#pragma unroll
    for (int off = 32; off > 0; off >>= 1) {
        al0 += __shfl_down(al0, off);
        al1 += __shfl_down(al1, off);
        ar0 += __shfl_down(ar0, off);
        ar1 += __shfl_down(ar1, off);
    }
    if (lane == 0) {
        xl2[node * 2 + 0] = al0 + wb[WO_B2L + 0];
        xl2[node * 2 + 1] = al1 + wb[WO_B2L + 1];
        xr2[node * 2 + 0] = ar0 + wb[WO_B2R + 0];
        xr2[node * 2 + 1] = ar1 + wb[WO_B2R + 1];
    }
}

// ================= fused layer-2 attention: 4 threads per dst node ===========
__global__ void __launch_bounds__(256) k_gat2(const int* __restrict__ rowptr,
                                              const int* __restrict__ csr,
                                              const float* __restrict__ xl2,
                                              const float* __restrict__ xr2,
                                              const float* __restrict__ wb,
                                              const unsigned* __restrict__ flag,
                                              void* __restrict__ dout) {
    int t = blockIdx.x * 256 + threadIdx.x;
    int d = t >> 2, part = t & 3;
    if (d >= N_NODES) return;
    float xr0 = xr2[d * 2 + 0], xr1 = xr2[d * 2 + 1];
    float at0 = wb[WO_ATT2], at1 = wb[WO_ATT2 + 1];
    int beg = rowptr[d], end = rowptr[d + 1];
    float l = 0.f, o0 = 0.f, o1 = 0.f;
    for (int j = beg + part; j < end; j += 4) {
        int s = csr[j];
        float b0 = xl2[s * 2 + 0], b1 = xl2[s * 2 + 1];
        float p = at0 * lrelu(b0 + xr0) + at1 * lrelu(b1 + xr1);
        float a = __expf(p);
        l += a;
        o0 = fmaf(a, b0, o0);
        o1 = fmaf(a, b1, o1);
    }
    // reduce the 4 parts (lanes 4d..4d+3 of one wave)
    l += __shfl_xor(l, 1);  o0 += __shfl_xor(o0, 1);  o1 += __shfl_xor(o1, 1);
    l += __shfl_xor(l, 2);  o0 += __shfl_xor(o0, 2);  o1 += __shfl_xor(o1, 2);
    if (part == 0) {
        float inv = 1.f / l;
        float v0 = fmaf(o0, inv, wb[WO_BIAS2 + 0]);
        float v1 = fmaf(o1, inv, wb[WO_BIAS2 + 1]);
        if (*flag) {
            ((__hip_bfloat16*)dout)[d * 2 + 0] = __float2bfloat16(v0);
            ((__hip_bfloat16*)dout)[d * 2 + 1] = __float2bfloat16(v1);
        } else {
            ((float*)dout)[d * 2 + 0] = v0;
            ((float*)dout)[d * 2 + 1] = v1;
        }
    }
}

extern "C" void kernel_launch(void* const* d_in, const int* in_sizes, int n_in,
                              void* d_out, int out_size, void* d_ws, size_t ws_size,
                              hipStream_t stream) {
    char* w = (char*)d_ws;
    unsigned* flag = (unsigned*)(w + (size_t)OFF_FLAG * 4);
    float* wb = (float*)(w + (size_t)OFF_W * 4);
    float* w2a = (float*)(w + (size_t)OFF_W2A * 4);
    unsigned short* wt = (unsigned short*)(w + (size_t)OFF_WT * 4);
    float* bcat = (float*)(w + (size_t)OFF_BCAT * 4);
    __hip_bfloat16* xlb = (__hip_bfloat16*)(w + (size_t)OFF_XLB * 4);
    __hip_bfloat16* xrb = (__hip_bfloat16*)(w + (size_t)OFF_XRB * 4);
    unsigned* pairs = (unsigned*)(w + (size_t)OFF_PAIRS * 4);
    int* csr = (int*)(w + (size_t)OFF_CSR * 4);
    int* rowptr = (int*)(w + (size_t)OFF_ROWPTR * 4);
    int* S = (int*)(w + (size_t)OFF_S * 4);
    float* xl2 = (float*)(w + (size_t)OFF_XL2 * 4);
    float* xr2 = (float*)(w + (size_t)OFF_XR2 * 4);
    unsigned short* h16 = (unsigned short*)(w + (size_t)OFF_H * 4);
    float* dl = (float*)(w + (size_t)OFF_DL * 4);
    float* dr = (float*)(w + (size_t)OFF_DR * 4);
    const int* esrc = (const int*)d_in[1];
    const int* edst = (const int*)d_in[2];

    // ---- fused prep + per-chunk histogram ----
    k_prep_hist<<<NCHUNK + PREP_BLKS, 256, 0, stream>>>(
        edst, S, (const unsigned short*)d_in[0],
        d_in[3], d_in[4], d_in[5], d_in[6], d_in[7], d_in[8],
        d_in[9], d_in[10], d_in[11], d_in[12], d_in[13], d_in[14],
        flag, wt, bcat, wb, w2a);

    // ---- CSR build ----
    k_pa_scan<<<1, 512, 0, stream>>>(S, rowptr);
    k_pa_scatter<<<NCHUNK, 256, 0, stream>>>(esrc, edst, S, pairs);
    k_bsort<<<NBUCK, 256, 0, stream>>>(S, pairs, rowptr, csr);

    // ---- layer-1 GEMM + att-dot epilogue ----
    k_gemm1_mfma<<<NPAD / 64, 256, 0, stream>>>(d_in[0], flag, wt, bcat,
                                                wb + WO_ATT1, xlb, xrb, dl, dr);

    // ---- layer-1 attention (separable score, grid-stride) ----
    k_gat1<<<GS_BLOCKS, 256, 0, stream>>>(rowptr, csr, xlb, xrb,
                                          wb + WO_ATT1, wb + WO_BIAS1,
                                          dl, dr, h16);

    // ---- layer-2 projection ----
    k_gemm2<<<(N_NODES + 3) / 4, 256, 0, stream>>>(h16, wb, w2a, xl2, xr2);

    // ---- layer-2 attention + output ----
    k_gat2<<<(4 * N_NODES + 255) / 256, 256, 0, stream>>>(rowptr, csr, xl2, xr2,
                                                          wb, flag, d_out);
}